// Round 9
// baseline (535.734 us; speedup 1.0000x reference)
//
#include <hip/hip_runtime.h>

#define NN 100000
#define EE 1600000
#define NBK 782          // coarse buckets = ceil(NN/128)
#define NBKP 784
#define NBLK 391         // edge blocks = ceil(EE/4096)
#define NBLKP 392
#define SETB 207         // setup blocks: 12 cvt + 192 transpose + 3 dots

typedef __attribute__((ext_vector_type(8))) __bf16 bf16x8;
typedef __attribute__((ext_vector_type(4))) float f32x4;
typedef unsigned short u16;

__device__ __forceinline__ float bf2f(u16 v) {
  union { unsigned u; float f; } x; x.u = ((unsigned)v) << 16; return x.f;
}
__device__ __forceinline__ u16 f2bf(float f) {
  union { unsigned u; float f; } x; x.f = f;
  x.u += 0x7fffu + ((x.u >> 16) & 1u);
  return (u16)(x.u >> 16);
}
__device__ __forceinline__ float lo_f(unsigned u) {
  union { unsigned u; float f; } x; x.u = u << 16; return x.f;
}
__device__ __forceinline__ float hi_f(unsigned u) {
  union { unsigned u; float f; } x; x.u = u & 0xffff0000u; return x.f;
}
__device__ __forceinline__ unsigned pack2(float a, float b) {
  return (unsigned)f2bf(a) | ((unsigned)f2bf(b) << 16);
}
__device__ __forceinline__ float lrelu(float x) { return x > 0.f ? x : 0.2f * x; }
__device__ __forceinline__ int clampi(int v, int hi) {
  return ((unsigned)v < (unsigned)hi) ? v : 0;
}
__device__ __forceinline__ float ldf(const void* p, size_t i, int fl) {
  return fl ? ((const float*)p)[i] : bf2f(((const u16*)p)[i]);
}

// ---- per-wave inline dtype detection ----
__device__ __forceinline__ int wave_fdetect(const u16* __restrict__ xb) {
  int lane = threadIdx.x & 63;
  int bad = 0;
#pragma unroll
  for (int j = 0; j < 4; ++j) {
    float a = fabsf(bf2f(xb[lane * 4 + j]));
    bad |= (!(a == a) || a > 1e6f) ? 1 : 0;
  }
  return (__ballot(bad) != 0ull) ? 1 : 0;
}
__device__ __forceinline__ int wave_mdetect(const int* __restrict__ ei) {
  int lane = threadIdx.x & 63;
  int v = (lane < 32) ? ei[2 * lane + 1] : 0;
  return (__ballot(v != 0) == 0ull) ? 1 : 0;
}

// ---------- sentinel fill ----------
__global__ void k_fillf(float* __restrict__ o, int n, float v) {
  int i = blockIdx.x * 256 + threadIdx.x;
  if (i < n) o[i] = v;
}

// ---------- fused setup (+ coarse edge histogram) ----------
struct CvtDesc { const void* src; u16* dst; int n; };
struct SetupArgs {
  CvtDesc cvt[12];
  const void* W[4]; u16* WT[4]; int WM[4];
  const void* dw[3]; const void* da[3]; int dm[3];
  float* cvals;
  const u16* xb;
  const int* ei;
  int* histM;
};
__global__ __launch_bounds__(256) void k_setup(SetupArgs a) {
  __shared__ int h[NBKP];
  int b = blockIdx.x, t = threadIdx.x;
  if (b >= SETB) {  // ---- ehist part ----
    int blk = b - SETB;
    int m_ = wave_mdetect(a.ei);
    for (int j = t; j < NBKP; j += 256) h[j] = 0;
    __syncthreads();
#pragma unroll
    for (int j = 0; j < 16; ++j) {
      int e = blk * 4096 + j * 256 + t;
      if (e < EE) {
        int d = m_ ? a.ei[2 * (size_t)(EE + e)] : a.ei[EE + e];
        d = clampi(d, NN);
        atomicAdd(&h[d >> 7], 1);
      }
    }
    __syncthreads();
    for (int j = t; j < NBKP; j += 256) a.histM[j * NBLKP + blk] = h[j];
    return;
  }
  if (b < 12) {  // small-vector conversions
    int fl = wave_fdetect(a.xb);
    const void* src = a.cvt[b].src; u16* dst = a.cvt[b].dst; int n = a.cvt[b].n;
    for (int i = t; i < n; i += 256)
      dst[i] = fl ? f2bf(((const float*)src)[i]) : ((const u16*)src)[i];
    return;
  }
  b -= 12;
  if (b < 192) {  // weight transposes
    int fl = wave_fdetect(a.xb);
    int wsel, lb;
    if (b < 64)       { wsel = 0; lb = b; }
    else if (b < 128) { wsel = 1; lb = b - 64; }
    else if (b < 160) { wsel = 2; lb = b - 128; }
    else              { wsel = 3; lb = b - 160; }
    int M = a.WM[wsel];
    int i = lb * 256 + t;
    if (i < 128 * M) {
      int k = i / M, m = i % M;
      a.WT[wsel][m * 128 + k] = f2bf(ldf(a.W[wsel], i, fl));
    }
    return;
  }
  b -= 192;
  if (b < 3) {  // c = dot(We[0,:], a_e)
    if (t < 64) {
      int fl = wave_fdetect(a.xb);
      float s = 0.f; int m = a.dm[b];
      for (int j = t; j < m; j += 64) s += ldf(a.dw[b], j, fl) * ldf(a.da[b], j, fl);
      for (int off = 32; off; off >>= 1) s += __shfl_xor(s, off);
      if (t == 0) a.cvals[b] = s;
    }
    return;
  }
}

// ---------- per-bucket exclusive prefix over blocks + bucket totals ----------
__global__ __launch_bounds__(512) void k_scanA(int* __restrict__ histM,
                                               int* __restrict__ binTot) {
  int b = blockIdx.x, t = threadIdx.x;
  int v = (t < NBLK) ? histM[b * NBLKP + t] : 0;
  int lane = t & 63, w = t >> 6;
  int sc = v;
  for (int off = 1; off < 64; off <<= 1) {
    int o = __shfl_up(sc, off); if (lane >= off) sc += o;
  }
  __shared__ int wt[8];
  if (lane == 63) wt[w] = sc;
  __syncthreads();
  int add = 0;
  for (int k = 0; k < w; ++k) add += wt[k];
  int excl = sc - v + add;
  if (t < NBLK) histM[b * NBLKP + t] = excl;
  if (t == 511) binTot[b] = excl;
}

// ---------- exclusive scan of bucket totals -> bucketBase ----------
__global__ __launch_bounds__(256) void k_scanB(const int* __restrict__ binTot,
                                               int* __restrict__ bucketBase,
                                               int* __restrict__ row_off) {
  int t = threadIdx.x;
  int v[4]; int s = 0;
#pragma unroll
  for (int j = 0; j < 4; ++j) {
    int idx = t * 4 + j;
    v[j] = (idx < NBK) ? binTot[idx] : 0;
    s += v[j];
  }
  int lane = t & 63, w = t >> 6;
  int sc = s;
  for (int off = 1; off < 64; off <<= 1) {
    int o = __shfl_up(sc, off); if (lane >= off) sc += o;
  }
  __shared__ int wt[4];
  if (lane == 63) wt[w] = sc;
  __syncthreads();
  int add = 0;
  for (int k = 0; k < w; ++k) add += wt[k];
  int ex = add + sc - s;
#pragma unroll
  for (int j = 0; j < 4; ++j) {
    int idx = t * 4 + j;
    if (idx <= NBK) bucketBase[idx] = ex;
    ex += v[j];
  }
  if (t == 0) row_off[NN] = EE;
}

// ---------- GEMM body ----------
template<bool DUAL>
__device__ __forceinline__ void gemm_body(
    int bid, int fl, const void* __restrict__ Araw,
    const u16* __restrict__ WT,
    const u16* __restrict__ avs, const u16* __restrict__ avd,
    u16* __restrict__ xl,
    float* __restrict__ asrc, float* __restrict__ adst,
    float2* __restrict__ asAB, float* __restrict__ adstB, int n) {
  const int K = 128;
  int lane = threadIdx.x & 63;
  int wave = threadIdx.x >> 6;
  int quad = lane >> 4;
  int l16 = lane & 15;
  int r0 = (bid * 4 + wave) * 16;
  if (r0 >= n) return;
  int arow = r0 + l16; if (arow >= n) arow = n - 1;
  bf16x8 afr[4];
  if (fl) {
    const float* af = (const float*)Araw + (size_t)arow * K + quad * 8;
#pragma unroll
    for (int kb = 0; kb < 4; ++kb) {
      float4 f0 = *(const float4*)(af + kb * 32);
      float4 f1 = *(const float4*)(af + kb * 32 + 4);
      union { bf16x8 v; u16 s[8]; } t;
      t.s[0] = f2bf(f0.x); t.s[1] = f2bf(f0.y); t.s[2] = f2bf(f0.z); t.s[3] = f2bf(f0.w);
      t.s[4] = f2bf(f1.x); t.s[5] = f2bf(f1.y); t.s[6] = f2bf(f1.z); t.s[7] = f2bf(f1.w);
      afr[kb] = t.v;
    }
  } else {
    const u16* ab = (const u16*)Araw + (size_t)arow * K + quad * 8;
#pragma unroll
    for (int kb = 0; kb < 4; ++kb) afr[kb] = *(const bf16x8*)(ab + kb * 32);
  }
  f32x4 acc[8];
#pragma unroll
  for (int nb = 0; nb < 8; ++nb) acc[nb] = (f32x4){0.f, 0.f, 0.f, 0.f};
#pragma unroll
  for (int nb = 0; nb < 8; ++nb) {
    const u16* bbase = WT + (size_t)(nb * 16 + l16) * K + quad * 8;
#pragma unroll
    for (int kb = 0; kb < 4; ++kb) {
      bf16x8 bfr = *(const bf16x8*)(bbase + kb * 32);
      acc[nb] = __builtin_amdgcn_mfma_f32_16x16x32_bf16(afr[kb], bfr, acc[nb], 0, 0, 0);
    }
  }
  float ps[2][4] = {{0,0,0,0},{0,0,0,0}}, pd[2][4] = {{0,0,0,0},{0,0,0,0}};
#pragma unroll
  for (int nb = 0; nb < 8; ++nb) {
    const int g = (DUAL && nb >= 4) ? 1 : 0;
    int col = nb * 16 + l16;
    float vs = bf2f(avs[col]), vd = bf2f(avd[col]);
#pragma unroll
    for (int r = 0; r < 4; ++r) {
      int row = r0 + quad * 4 + r;
      float v = acc[nb][r];
      if (row < n) xl[(size_t)row * 128 + col] = f2bf(v);
      ps[g][r] += v * vs;
      pd[g][r] += v * vd;
    }
  }
#pragma unroll
  for (int off = 1; off < 16; off <<= 1) {
#pragma unroll
    for (int r = 0; r < 4; ++r) {
      ps[0][r] += __shfl_xor(ps[0][r], off);
      pd[0][r] += __shfl_xor(pd[0][r], off);
      if (DUAL) {
        ps[1][r] += __shfl_xor(ps[1][r], off);
        pd[1][r] += __shfl_xor(pd[1][r], off);
      }
    }
  }
  if (l16 == 0) {
#pragma unroll
    for (int r = 0; r < 4; ++r) {
      int row = r0 + quad * 4 + r;
      if (row < n) {
        if (DUAL) {
          asAB[row] = make_float2(ps[0][r], ps[1][r]);
          adst[row] = pd[0][r]; adstB[row] = pd[1][r];
        } else {
          asrc[row] = ps[0][r]; adst[row] = pd[0][r];
        }
      }
    }
  }
}

// ---------- MERGED: layer-0 GEMM FIRST, then bucket scatter blocks ----------
__global__ __launch_bounds__(256) void k_esgemm(
    const int* __restrict__ ei, const void* __restrict__ ew,
    const u16* __restrict__ xb, const int* __restrict__ histM,
    const int* __restrict__ bucketBase, int2* __restrict__ stage,
    const void* __restrict__ Araw, const u16* __restrict__ WT,
    const u16* __restrict__ avs, const u16* __restrict__ avd,
    u16* __restrict__ xl, float* __restrict__ asrc, float* __restrict__ adst,
    int n, int gemmBlocks) {
  __shared__ int lbase[NBKP];
  __shared__ int cur[NBKP];
  if ((int)blockIdx.x < gemmBlocks) {  // ---- gemm0 part (runs first) ----
    int fl = wave_fdetect(xb);
    gemm_body<false>(blockIdx.x, fl, Araw, WT, avs, avd,
                     xl, asrc, adst, nullptr, nullptr, n);
    return;
  }
  // ---- escatter part ----
  int blk = (int)blockIdx.x - gemmBlocks, t = threadIdx.x;
  int m_ = wave_mdetect(ei);
  int fl = wave_fdetect(xb);
  for (int j = t; j < NBKP; j += 256) {
    int bb = (j < NBK) ? (bucketBase[j] + histM[j * NBLKP + blk]) : 0;
    lbase[j] = bb; cur[j] = 0;
  }
  __syncthreads();
#pragma unroll
  for (int j = 0; j < 16; ++j) {
    int e = blk * 4096 + j * 256 + t;
    if (e < EE) {
      int s = m_ ? ei[2 * (size_t)e] : ei[e];
      int d = m_ ? ei[2 * (size_t)(EE + e)] : ei[EE + e];
      s = clampi(s, NN);
      d = clampi(d, NN);
      int bin = d >> 7, low = d & 127;
      int r = atomicAdd(&cur[bin], 1);
      int pos = lbase[bin] + r;
      if (pos >= 0 && pos < EE)
        stage[pos] = make_int2(s, (low << 16) | (int)f2bf(ldf(ew, e, fl)));
    }
  }
}

// ---------- per-bucket counting sort -> CSR + row_off + la + degree bins ----------
__global__ __launch_bounds__(256) void k_bucket(
    const int2* __restrict__ stage, const int* __restrict__ bucketBase,
    int2* __restrict__ edges, int* __restrict__ row_off, float* __restrict__ la,
    int* __restrict__ degM) {
  __shared__ int hist[128];
  __shared__ float wsum[128];
  __shared__ int pref[128];
  __shared__ int cur[128];
  __shared__ int dh[32];
  int b = blockIdx.x, t = threadIdx.x;
  int base = bucketBase[b], n = bucketBase[b + 1] - base;
  if (t < 128) { hist[t] = 0; wsum[t] = 0.f; cur[t] = 0; }
  if (t >= 128 && t < 160) dh[t - 128] = 0;
  __syncthreads();
  for (int i = t; i < n; i += 256) {
    int2 it = stage[base + i];
    int bin = (it.y >> 16) & 127;
    atomicAdd(&hist[bin], 1);
    atomicAdd(&wsum[bin], bf2f((u16)(it.y & 0xffff)));
  }
  __syncthreads();
  if (t == 0) {
    int run = 0;
    for (int j = 0; j < 128; ++j) { pref[j] = run; run += hist[j]; }
  }
  __syncthreads();
  if (t < 128) {
    int d = b * 128 + t;
    if (d < NN) {
      row_off[d] = base + pref[t];
      la[d] = hist[t] ? wsum[t] / (float)hist[t] : 0.f;
      int bin = hist[t] < 32 ? hist[t] : 31;
      atomicAdd(&dh[bin], 1);
    }
  }
  __syncthreads();
  if (t < 32) degM[t * NBKP + b] = dh[t];
  for (int i = t; i < n; i += 256) {
    int2 it = stage[base + i];
    int bin = (it.y >> 16) & 127;
    int r = atomicAdd(&cur[bin], 1);
    edges[base + pref[bin] + r] = it;
  }
}

// ---------- degree-bin scan: 32 blocks, each scans 782 cols of degM ----------
__global__ __launch_bounds__(512) void k_scanD(int* __restrict__ degM,
                                               int* __restrict__ binTotD) {
  __shared__ int wt[8];
  __shared__ int carrySh;
  int b = blockIdx.x, t = threadIdx.x;
  if (t == 0) carrySh = 0;
  __syncthreads();
  for (int half = 0; half < 2; ++half) {
    int col = half * 512 + t;
    int v = (col < NBK) ? degM[b * NBKP + col] : 0;
    int lane = t & 63, w = t >> 6;
    int sc = v;
    for (int off = 1; off < 64; off <<= 1) {
      int o = __shfl_up(sc, off); if (lane >= off) sc += o;
    }
    if (lane == 63) wt[w] = sc;
    __syncthreads();
    int add = 0;
    for (int k = 0; k < w; ++k) add += wt[k];
    int excl = carrySh + add + sc - v;
    if (col < NBK) degM[b * NBKP + col] = excl;
    __syncthreads();
    if (t == 511) carrySh = excl + v;
    __syncthreads();
  }
  if (t == 0) binTotD[b] = carrySh;
}

// ---------- exclusive scan of 32 degree-bin totals ----------
__global__ void k_scanE(const int* __restrict__ binTotD, int* __restrict__ binBaseD) {
  int t = threadIdx.x;
  int v = (t < 32) ? binTotD[t] : 0;
  int sc = v;
  for (int off = 1; off < 64; off <<= 1) {
    int o = __shfl_up(sc, off); if (t >= off) sc += o;
  }
  if (t < 32) binBaseD[t] = sc - v;
}

// ---------- scatter node ids into degree-sorted perm ----------
__global__ __launch_bounds__(128) void k_dscatter(
    const int* __restrict__ row_off, const int* __restrict__ degM,
    const int* __restrict__ binBaseD, int* __restrict__ perm) {
  __shared__ int cur[32];
  int b = blockIdx.x, t = threadIdx.x;
  if (t < 32) cur[t] = 0;
  __syncthreads();
  int d = b * 128 + t;
  if (d < NN) {
    int deg = row_off[d + 1] - row_off[d];
    int bin = deg < 32 ? deg : 31;
    int r = atomicAdd(&cur[bin], 1);
    int pos = binBaseD[bin] + degM[bin * NBKP + b] + r;
    if (pos >= 0 && pos < NN) perm[pos] = d;
  }
}

// ---------- standalone GEMM (bf16 A) ----------
template<bool DUAL>
__global__ __launch_bounds__(256) void k_gemm(
    const u16* __restrict__ A, const u16* __restrict__ WT,
    const u16* __restrict__ avs, const u16* __restrict__ avd,
    u16* __restrict__ xl, float* __restrict__ asrc, float* __restrict__ adst,
    float2* __restrict__ asAB, float* __restrict__ adstB, int n) {
  gemm_body<DUAL>(blockIdx.x, 0, A, WT, avs, avd, xl, asrc, adst, asAB, adstB, n);
}

// ---------- FUSED softmax+aggregation, 16 lanes/node, degree-sorted perm ----------
__global__ __launch_bounds__(256) void k_agg(
    const int* __restrict__ perm,
    const int* __restrict__ row_off, const int2* __restrict__ edges,
    const float* __restrict__ asrc, const float* __restrict__ adst,
    const float* __restrict__ la, const float* __restrict__ cptr,
    const u16* __restrict__ xl, const u16* __restrict__ bias,
    u16* __restrict__ out, int n) {
  __shared__ float lp[16][16];
  __shared__ int lsv[16][16];
  int tid = blockIdx.x * 256 + threadIdx.x;
  int wid = tid >> 4;
  if (wid >= n) return;
  int d = perm[wid];
  int l = threadIdx.x & 15;
  int grp = threadIdx.x >> 4;
  float c = cptr[0];
  float ad = adst[d];
  float aL = lrelu(asrc[d] + ad + c * la[d]);
  float lsum = 0.f;
  int4 su = *(const int4*)(xl + (size_t)d * 128 + l * 8);
  float A0 = lo_f(su.x), A1 = hi_f(su.x), A2 = lo_f(su.y), A3 = hi_f(su.y);
  float A4 = lo_f(su.z), A5 = hi_f(su.z), A6 = lo_f(su.w), A7 = hi_f(su.w);
  float B0 = 0.f, B1 = 0.f, B2 = 0.f, B3 = 0.f, B4 = 0.f, B5 = 0.f, B6 = 0.f, B7 = 0.f;
  int beg = row_off[d], end = row_off[d + 1];
  for (int base = beg; base < end; base += 16) {
    int i = base + l;
    bool v = i < end;
    int2 ev = v ? edges[i] : make_int2(0, 0);
    float e = 0.f;
    if (v) e = __expf(lrelu(asrc[ev.x] + ad + c * bf2f((u16)(ev.y & 0xffff))) - aL);
    lsum += e;
    lp[grp][l] = e; lsv[grp][l] = ev.x;
    int cnt = end - base; if (cnt > 16) cnt = 16;
    int j = 0;
    for (; j + 4 <= cnt; j += 4) {
      float p0 = lp[grp][j + 0]; int s0 = lsv[grp][j + 0];
      float p1 = lp[grp][j + 1]; int s1 = lsv[grp][j + 1];
      float p2 = lp[grp][j + 2]; int s2 = lsv[grp][j + 2];
      float p3 = lp[grp][j + 3]; int s3 = lsv[grp][j + 3];
      int4 u0 = *(const int4*)(xl + (size_t)s0 * 128 + l * 8);
      int4 u1 = *(const int4*)(xl + (size_t)s1 * 128 + l * 8);
      int4 u2 = *(const int4*)(xl + (size_t)s2 * 128 + l * 8);
      int4 u3 = *(const int4*)(xl + (size_t)s3 * 128 + l * 8);
      A0 = fmaf(p0, lo_f(u0.x), A0); A1 = fmaf(p0, hi_f(u0.x), A1);
      A2 = fmaf(p0, lo_f(u0.y), A2); A3 = fmaf(p0, hi_f(u0.y), A3);
      A4 = fmaf(p0, lo_f(u0.z), A4); A5 = fmaf(p0, hi_f(u0.z), A5);
      A6 = fmaf(p0, lo_f(u0.w), A6); A7 = fmaf(p0, hi_f(u0.w), A7);
      B0 = fmaf(p1, lo_f(u1.x), B0); B1 = fmaf(p1, hi_f(u1.x), B1);
      B2 = fmaf(p1, lo_f(u1.y), B2); B3 = fmaf(p1, hi_f(u1.y), B3);
      B4 = fmaf(p1, lo_f(u1.z), B4); B5 = fmaf(p1, hi_f(u1.z), B5);
      B6 = fmaf(p1, lo_f(u1.w), B6); B7 = fmaf(p1, hi_f(u1.w), B7);
      A0 = fmaf(p2, lo_f(u2.x), A0); A1 = fmaf(p2, hi_f(u2.x), A1);
      A2 = fmaf(p2, lo_f(u2.y), A2); A3 = fmaf(p2, hi_f(u2.y), A3);
      A4 = fmaf(p2, lo_f(u2.z), A4); A5 = fmaf(p2, hi_f(u2.z), A5);
      A6 = fmaf(p2, lo_f(u2.w), A6); A7 = fmaf(p2, hi_f(u2.w), A7);
      B0 = fmaf(p3, lo_f(u3.x), B0); B1 = fmaf(p3, hi_f(u3.x), B1);
      B2 = fmaf(p3, lo_f(u3.y), B2); B3 = fmaf(p3, hi_f(u3.y), B3);
      B4 = fmaf(p3, lo_f(u3.z), B4); B5 = fmaf(p3, hi_f(u3.z), B5);
      B6 = fmaf(p3, lo_f(u3.w), B6); B7 = fmaf(p3, hi_f(u3.w), B7);
    }
    for (; j + 2 <= cnt; j += 2) {
      float p0 = lp[grp][j];     int s0 = lsv[grp][j];
      float p1 = lp[grp][j + 1]; int s1 = lsv[grp][j + 1];
      int4 u0 = *(const int4*)(xl + (size_t)s0 * 128 + l * 8);
      int4 u1 = *(const int4*)(xl + (size_t)s1 * 128 + l * 8);
      A0 = fmaf(p0, lo_f(u0.x), A0); A1 = fmaf(p0, hi_f(u0.x), A1);
      A2 = fmaf(p0, lo_f(u0.y), A2); A3 = fmaf(p0, hi_f(u0.y), A3);
      A4 = fmaf(p0, lo_f(u0.z), A4); A5 = fmaf(p0, hi_f(u0.z), A5);
      A6 = fmaf(p0, lo_f(u0.w), A6); A7 = fmaf(p0, hi_f(u0.w), A7);
      B0 = fmaf(p1, lo_f(u1.x), B0); B1 = fmaf(p1, hi_f(u1.x), B1);
      B2 = fmaf(p1, lo_f(u1.y), B2); B3 = fmaf(p1, hi_f(u1.y), B3);
      B4 = fmaf(p1, lo_f(u1.z), B4); B5 = fmaf(p1, hi_f(u1.z), B5);
      B6 = fmaf(p1, lo_f(u1.w), B6); B7 = fmaf(p1, hi_f(u1.w), B7);
    }
    if (j < cnt) {
      float p0 = lp[grp][j]; int s0 = lsv[grp][j];
      int4 u0 = *(const int4*)(xl + (size_t)s0 * 128 + l * 8);
      A0 = fmaf(p0, lo_f(u0.x), A0); A1 = fmaf(p0, hi_f(u0.x), A1);
      A2 = fmaf(p0, lo_f(u0.y), A2); A3 = fmaf(p0, hi_f(u0.y), A3);
      A4 = fmaf(p0, lo_f(u0.z), A4); A5 = fmaf(p0, hi_f(u0.z), A5);
      A6 = fmaf(p0, lo_f(u0.w), A6); A7 = fmaf(p0, hi_f(u0.w), A7);
    }
  }
  A0 += B0; A1 += B1; A2 += B2; A3 += B3; A4 += B4; A5 += B5; A6 += B6; A7 += B7;
#pragma unroll
  for (int off = 1; off < 16; off <<= 1) lsum += __shfl_xor(lsum, off);
  float inv = 1.f / (lsum + 1.f);
  int4 bv = *(const int4*)(bias + l * 8);
  float o0 = fmaxf(fmaf(A0, inv, lo_f((unsigned)bv.x)), 0.f);
  float o1 = fmaxf(fmaf(A1, inv, hi_f((unsigned)bv.x)), 0.f);
  float o2 = fmaxf(fmaf(A2, inv, lo_f((unsigned)bv.y)), 0.f);
  float o3 = fmaxf(fmaf(A3, inv, hi_f((unsigned)bv.y)), 0.f);
  float o4 = fmaxf(fmaf(A4, inv, lo_f((unsigned)bv.z)), 0.f);
  float o5 = fmaxf(fmaf(A5, inv, hi_f((unsigned)bv.z)), 0.f);
  float o6 = fmaxf(fmaf(A6, inv, lo_f((unsigned)bv.w)), 0.f);
  float o7 = fmaxf(fmaf(A7, inv, hi_f((unsigned)bv.w)), 0.f);
  int4 ov;
  ov.x = (int)pack2(o0, o1); ov.y = (int)pack2(o2, o3);
  ov.z = (int)pack2(o4, o5); ov.w = (int)pack2(o6, o7);
  *(int4*)(out + (size_t)d * 128 + l * 8) = ov;
}

// ---------- FUSED dual-head, 16 lanes/node, degree-sorted perm ----------
__global__ __launch_bounds__(256) void k_aggh(
    const int* __restrict__ perm,
    const int* __restrict__ row_off, const int2* __restrict__ edges,
    const float2* __restrict__ asAB, const float* __restrict__ adA,
    const float* __restrict__ adB,
    const float* __restrict__ la, const float* __restrict__ cptr,
    const u16* __restrict__ xl, const u16* __restrict__ bias,
    float* __restrict__ outf, int n) {
  __shared__ float lpA[16][16];
  __shared__ float lpB[16][16];
  __shared__ int lsv[16][16];
  int tid = blockIdx.x * 256 + threadIdx.x;
  int wid = tid >> 4;
  if (wid >= n) return;
  int d = perm[wid];
  int l = threadIdx.x & 15;
  int grp = threadIdx.x >> 4;
  bool isMu = l < 8;
  float c = cptr[0];
  float adAd = adA[d], adBd = adB[d];
  float2 abd = asAB[d];
  float aLA = lrelu(abd.x + adAd + c * la[d]);
  float aLB = lrelu(abd.y + adBd);
  float lsA = 0.f, lsB = 0.f;
  int4 su = *(const int4*)(xl + (size_t)d * 128 + l * 8);
  float A0 = lo_f(su.x), A1 = hi_f(su.x), A2 = lo_f(su.y), A3 = hi_f(su.y);
  float A4 = lo_f(su.z), A5 = hi_f(su.z), A6 = lo_f(su.w), A7 = hi_f(su.w);
  float B0 = 0.f, B1 = 0.f, B2 = 0.f, B3 = 0.f, B4 = 0.f, B5 = 0.f, B6 = 0.f, B7 = 0.f;
  int beg = row_off[d], end = row_off[d + 1];
  for (int base = beg; base < end; base += 16) {
    int i = base + l;
    bool v = i < end;
    int2 ev = v ? edges[i] : make_int2(0, 0);
    float eA = 0.f, eB = 0.f;
    if (v) {
      float2 ab = asAB[ev.x];
      eA = __expf(lrelu(ab.x + adAd + c * bf2f((u16)(ev.y & 0xffff))) - aLA);
      eB = __expf(lrelu(ab.y + adBd) - aLB);
    }
    lsA += eA; lsB += eB;
    lpA[grp][l] = eA; lpB[grp][l] = eB; lsv[grp][l] = ev.x;
    const float* lpp = isMu ? lpA[grp] : lpB[grp];
    int cnt = end - base; if (cnt > 16) cnt = 16;
    int j = 0;
    for (; j + 4 <= cnt; j += 4) {
      float p0 = lpp[j + 0]; int s0 = lsv[grp][j + 0];
      float p1 = lpp[j + 1]; int s1 = lsv[grp][j + 1];
      float p2 = lpp[j + 2]; int s2 = lsv[grp][j + 2];
      float p3 = lpp[j + 3]; int s3 = lsv[grp][j + 3];
      int4 u0 = *(const int4*)(xl + (size_t)s0 * 128 + l * 8);
      int4 u1 = *(const int4*)(xl + (size_t)s1 * 128 + l * 8);
      int4 u2 = *(const int4*)(xl + (size_t)s2 * 128 + l * 8);
      int4 u3 = *(const int4*)(xl + (size_t)s3 * 128 + l * 8);
      A0 = fmaf(p0, lo_f(u0.x), A0); A1 = fmaf(p0, hi_f(u0.x), A1);
      A2 = fmaf(p0, lo_f(u0.y), A2); A3 = fmaf(p0, hi_f(u0.y), A3);
      A4 = fmaf(p0, lo_f(u0.z), A4); A5 = fmaf(p0, hi_f(u0.z), A5);
      A6 = fmaf(p0, lo_f(u0.w), A6); A7 = fmaf(p0, hi_f(u0.w), A7);
      B0 = fmaf(p1, lo_f(u1.x), B0); B1 = fmaf(p1, hi_f(u1.x), B1);
      B2 = fmaf(p1, lo_f(u1.y), B2); B3 = fmaf(p1, hi_f(u1.y), B3);
      B4 = fmaf(p1, lo_f(u1.z), B4); B5 = fmaf(p1, hi_f(u1.z), B5);
      B6 = fmaf(p1, lo_f(u1.w), B6); B7 = fmaf(p1, hi_f(u1.w), B7);
      A0 = fmaf(p2, lo_f(u2.x), A0); A1 = fmaf(p2, hi_f(u2.x), A1);
      A2 = fmaf(p2, lo_f(u2.y), A2); A3 = fmaf(p2, hi_f(u2.y), A3);
      A4 = fmaf(p2, lo_f(u2.z), A4); A5 = fmaf(p2, hi_f(u2.z), A5);
      A6 = fmaf(p2, lo_f(u2.w), A6); A7 = fmaf(p2, hi_f(u2.w), A7);
      B0 = fmaf(p3, lo_f(u3.x), B0); B1 = fmaf(p3, hi_f(u3.x), B1);
      B2 = fmaf(p3, lo_f(u3.y), B2); B3 = fmaf(p3, hi_f(u3.y), B3);
      B4 = fmaf(p3, lo_f(u3.z), B4); B5 = fmaf(p3, hi_f(u3.z), B5);
      B6 = fmaf(p3, lo_f(u3.w), B6); B7 = fmaf(p3, hi_f(u3.w), B7);
    }
    for (; j + 2 <= cnt; j += 2) {
      float p0 = lpp[j];     int s0 = lsv[grp][j];
      float p1 = lpp[j + 1]; int s1 = lsv[grp][j + 1];
      int4 u0 = *(const int4*)(xl + (size_t)s0 * 128 + l * 8);
      int4 u1 = *(const int4*)(xl + (size_t)s1 * 128 + l * 8);
      A0 = fmaf(p0, lo_f(u0.x), A0); A1 = fmaf(p0, hi_f(u0.x), A1);
      A2 = fmaf(p0, lo_f(u0.y), A2); A3 = fmaf(p0, hi_f(u0.y), A3);
      A4 = fmaf(p0, lo_f(u0.z), A4); A5 = fmaf(p0, hi_f(u0.z), A5);
      A6 = fmaf(p0, lo_f(u0.w), A6); A7 = fmaf(p0, hi_f(u0.w), A7);
      B0 = fmaf(p1, lo_f(u1.x), B0); B1 = fmaf(p1, hi_f(u1.x), B1);
      B2 = fmaf(p1, lo_f(u1.y), B2); B3 = fmaf(p1, hi_f(u1.y), B3);
      B4 = fmaf(p1, lo_f(u1.z), B4); B5 = fmaf(p1, hi_f(u1.z), B5);
      B6 = fmaf(p1, lo_f(u1.w), B6); B7 = fmaf(p1, hi_f(u1.w), B7);
    }
    if (j < cnt) {
      float p0 = lpp[j]; int s0 = lsv[grp][j];
      int4 u0 = *(const int4*)(xl + (size_t)s0 * 128 + l * 8);
      A0 = fmaf(p0, lo_f(u0.x), A0); A1 = fmaf(p0, hi_f(u0.x), A1);
      A2 = fmaf(p0, lo_f(u0.y), A2); A3 = fmaf(p0, hi_f(u0.y), A3);
      A4 = fmaf(p0, lo_f(u0.z), A4); A5 = fmaf(p0, hi_f(u0.z), A5);
      A6 = fmaf(p0, lo_f(u0.w), A6); A7 = fmaf(p0, hi_f(u0.w), A7);
    }
  }
  A0 += B0; A1 += B1; A2 += B2; A3 += B3; A4 += B4; A5 += B5; A6 += B6; A7 += B7;
#pragma unroll
  for (int off = 1; off < 16; off <<= 1) {
    lsA += __shfl_xor(lsA, off);
    lsB += __shfl_xor(lsB, off);
  }
  float inv = 1.f / ((isMu ? lsA : lsB) + 1.f);
  int4 bv = *(const int4*)(bias + l * 8);
  float4 oa, ob;
  oa.x = fmaf(A0, inv, lo_f((unsigned)bv.x));
  oa.y = fmaf(A1, inv, hi_f((unsigned)bv.x));
  oa.z = fmaf(A2, inv, lo_f((unsigned)bv.y));
  oa.w = fmaf(A3, inv, hi_f((unsigned)bv.y));
  ob.x = fmaf(A4, inv, lo_f((unsigned)bv.z));
  ob.y = fmaf(A5, inv, hi_f((unsigned)bv.z));
  ob.z = fmaf(A6, inv, lo_f((unsigned)bv.w));
  ob.w = fmaf(A7, inv, hi_f((unsigned)bv.w));
  float* obase = isMu ? (outf + (size_t)d * 64 + l * 8)
                      : (outf + (size_t)NN * 64 + (size_t)d * 64 + (l - 8) * 8);
  *(float4*)obase = oa;
  *(float4*)(obase + 4) = ob;
}

extern "C" void kernel_launch(void* const* d_in, const int* in_sizes, int n_in,
                              void* d_out, int out_size, void* d_ws, size_t ws_size,
                              hipStream_t stream) {
  (void)in_sizes; (void)n_in;
  const int* ei = (const int*)d_in[1];
  const u16* xb = (const u16*)d_in[0];
  float* outf = (float*)d_out;  // fp32 output

  // d_out scratch (dead before its region is written as output):
  //   histM: [0 .. 1.23MB)    consumed by k_esgemm/scanA
  //   stage: [2MB .. 14.8MB)  consumed by k_bucket
  //   degM:  [15MB .. 15.1MB) consumed by k_dscatter (before agg L1 -> h1 @ [0,25.6MB))
  u16* regionA = (u16*)d_out;                     // h1 (agg L1 output)
  u16* regionB = (u16*)d_out + (size_t)NN * 128;  // h0 (agg L0 output)
  int* histM = (int*)d_out;
  int2* stage = (int2*)((char*)d_out + (size_t)2 * 1024 * 1024);
  int* degM = (int*)((char*)d_out + (size_t)15 * 1024 * 1024);  // [32][NBKP]

  char* p = (char*)d_ws;
  auto alloc = [&](size_t bytes) -> char* {
    char* r = p; p += (bytes + 255) & ~(size_t)255; return r;
  };
  int*   row_off   = (int*)alloc((NN + 1) * 4);
  int*   binTot    = (int*)alloc(NBKP * 4);
  int*   bucketBase= (int*)alloc((NBKP + 2) * 4);
  int*   binTotD   = (int*)alloc(64 * 4);
  int*   binBaseD  = (int*)alloc(64 * 4);
  int*   perm      = (int*)alloc(NN * 4);
  float* la        = (float*)alloc(NN * 4);
  float* asrcA     = (float*)alloc(NN * 4);
  float* adstA     = (float*)alloc(NN * 4);
  float* adstB     = (float*)alloc(NN * 4);
  float2* asAB     = (float2*)alloc((size_t)NN * 8);
  int2*  edges     = (int2*)alloc((size_t)EE * 8);
  u16*   WT0       = (u16*)alloc(128 * 128 * 2);
  u16*   WT1       = (u16*)alloc(128 * 128 * 2);
  u16*   WTh       = (u16*)alloc(128 * 128 * 2);
  float* cvals     = (float*)alloc(16);
  u16*   vecc      = (u16*)alloc(9 * 256);
  u16*   xl        = (u16*)alloc((size_t)NN * 128 * 2);  // 25.6 MB

  size_t NEED = (size_t)(p - (char*)d_ws);  // ~41.7 MB (== R4 proven fit)
  if (ws_size < NEED) {
    k_fillf<<<(out_size + 255) / 256, 256, 0, stream>>>(outf, out_size, 0.125f);
    return;
  }

  u16* as0c = vecc + 0 * 128; u16* ad0c = vecc + 1 * 128; u16* b0c = vecc + 2 * 128;
  u16* as1c = vecc + 3 * 128; u16* ad1c = vecc + 4 * 128; u16* b1c = vecc + 5 * 128;
  u16* hvs  = vecc + 6 * 128; u16* hvd  = vecc + 7 * 128; u16* bh  = vecc + 8 * 128;

  // ---- fused setup + ehist ----
  SetupArgs sa;
  sa.cvt[0]  = {d_in[4],  as0c, 128};
  sa.cvt[1]  = {d_in[5],  ad0c, 128};
  sa.cvt[2]  = {d_in[8],  b0c,  128};
  sa.cvt[3]  = {d_in[10], as1c, 128};
  sa.cvt[4]  = {d_in[11], ad1c, 128};
  sa.cvt[5]  = {d_in[14], b1c,  128};
  sa.cvt[6]  = {d_in[16], hvs,      64};  // asm
  sa.cvt[7]  = {d_in[22], hvs + 64, 64};  // asl
  sa.cvt[8]  = {d_in[17], hvd,      64};  // adm
  sa.cvt[9]  = {d_in[23], hvd + 64, 64};  // adl
  sa.cvt[10] = {d_in[20], bh,       64};  // bm
  sa.cvt[11] = {d_in[24], bh + 64,  64};  // bl
  sa.W[0] = d_in[3];  sa.WT[0] = WT0;            sa.WM[0] = 128;
  sa.W[1] = d_in[9];  sa.WT[1] = WT1;            sa.WM[1] = 128;
  sa.W[2] = d_in[15]; sa.WT[2] = WTh;            sa.WM[2] = 64;
  sa.W[3] = d_in[21]; sa.WT[3] = WTh + 64 * 128; sa.WM[3] = 64;
  sa.dw[0] = d_in[7];  sa.da[0] = d_in[6];  sa.dm[0] = 128;
  sa.dw[1] = d_in[13]; sa.da[1] = d_in[12]; sa.dm[1] = 128;
  sa.dw[2] = d_in[19]; sa.da[2] = d_in[18]; sa.dm[2] = 64;
  sa.cvals = cvals; sa.xb = xb; sa.ei = ei; sa.histM = histM;
  k_setup<<<SETB + NBLK, 256, 0, stream>>>(sa);

  const int gblocks = (((NN + 15) / 16) + 3) / 4;
  const int eblocks16 = (int)(((size_t)NN * 16 + 255) / 256);

  // ---- CSR offsets ----
  k_scanA<<<NBK, 512, 0, stream>>>(histM, binTot);
  k_scanB<<<1, 256, 0, stream>>>(binTot, bucketBase, row_off);
  // ---- layer-0 GEMM (blocks first) co-resident with bucket scatter ----
  k_esgemm<<<gblocks + NBLK, 256, 0, stream>>>(ei, d_in[2], xb, histM, bucketBase,
                                               stage, d_in[0], WT0, as0c, ad0c,
                                               xl, asrcA, adstA, NN, gblocks);
  k_bucket<<<NBK, 256, 0, stream>>>(stage, bucketBase, edges, row_off, la, degM);
  // ---- degree-sorted node permutation ----
  k_scanD<<<32, 512, 0, stream>>>(degM, binTotD);
  k_scanE<<<1, 64, 0, stream>>>(binTotD, binBaseD);
  k_dscatter<<<NBK, 128, 0, stream>>>(row_off, degM, binBaseD, perm);

  // ---- layer 0 aggregation: xl -> h0(regionB) ----
  k_agg<<<eblocks16, 256, 0, stream>>>(perm, row_off, edges, asrcA, adstA, la,
                                       cvals + 0, xl, b0c, regionB, NN);
  // ---- layer 1 ----
  k_gemm<false><<<gblocks, 256, 0, stream>>>(regionB, WT1, as1c, ad1c,
                                             xl, asrcA, adstA, nullptr, nullptr, NN);
  k_agg<<<eblocks16, 256, 0, stream>>>(perm, row_off, edges, asrcA, adstA, la,
                                       cvals + 1, xl, b1c, regionA, NN);
  // ---- heads ----
  k_gemm<true><<<gblocks, 256, 0, stream>>>(regionA, WTh, hvs, hvd,
                                            xl, nullptr, adstA, asAB, adstB, NN);
  k_aggh<<<eblocks16, 256, 0, stream>>>(perm, row_off, edges, asAB, adstA, adstB,
                                        la, cvals + 2, xl, bh, outf, NN);
}

// Round 10
// 523.173 us; speedup vs baseline: 1.0240x; 1.0240x over previous
//
#include <hip/hip_runtime.h>

#define NN 100000
#define EE 1600000
#define NBK 782          // coarse buckets = ceil(NN/128)
#define NBKP 784
#define NBLK2 1564       // edge blocks = ceil(EE/1024)
#define NBLK2P 1568
#define SETB 207         // setup blocks: 12 cvt + 192 transpose + 3 dots

typedef __attribute__((ext_vector_type(8))) __bf16 bf16x8;
typedef __attribute__((ext_vector_type(4))) float f32x4;
typedef unsigned short u16;

__device__ __forceinline__ float bf2f(u16 v) {
  union { unsigned u; float f; } x; x.u = ((unsigned)v) << 16; return x.f;
}
__device__ __forceinline__ u16 f2bf(float f) {
  union { unsigned u; float f; } x; x.f = f;
  x.u += 0x7fffu + ((x.u >> 16) & 1u);
  return (u16)(x.u >> 16);
}
__device__ __forceinline__ float lo_f(unsigned u) {
  union { unsigned u; float f; } x; x.u = u << 16; return x.f;
}
__device__ __forceinline__ float hi_f(unsigned u) {
  union { unsigned u; float f; } x; x.u = u & 0xffff0000u; return x.f;
}
__device__ __forceinline__ unsigned pack2(float a, float b) {
  return (unsigned)f2bf(a) | ((unsigned)f2bf(b) << 16);
}
__device__ __forceinline__ float lrelu(float x) { return x > 0.f ? x : 0.2f * x; }
__device__ __forceinline__ int clampi(int v, int hi) {
  return ((unsigned)v < (unsigned)hi) ? v : 0;
}
__device__ __forceinline__ float ldf(const void* p, size_t i, int fl) {
  return fl ? ((const float*)p)[i] : bf2f(((const u16*)p)[i]);
}

// ---- per-wave inline dtype detection ----
__device__ __forceinline__ int wave_fdetect(const u16* __restrict__ xb) {
  int lane = threadIdx.x & 63;
  int bad = 0;
#pragma unroll
  for (int j = 0; j < 4; ++j) {
    float a = fabsf(bf2f(xb[lane * 4 + j]));
    bad |= (!(a == a) || a > 1e6f) ? 1 : 0;
  }
  return (__ballot(bad) != 0ull) ? 1 : 0;
}
__device__ __forceinline__ int wave_mdetect(const int* __restrict__ ei) {
  int lane = threadIdx.x & 63;
  int v = (lane < 32) ? ei[2 * lane + 1] : 0;
  return (__ballot(v != 0) == 0ull) ? 1 : 0;
}

// ---------- sentinel fill ----------
__global__ void k_fillf(float* __restrict__ o, int n, float v) {
  int i = blockIdx.x * 256 + threadIdx.x;
  if (i < n) o[i] = v;
}

// ---------- fused setup (+ coarse edge histogram, 1564 fine blocks) ----------
struct CvtDesc { const void* src; u16* dst; int n; };
struct SetupArgs {
  CvtDesc cvt[12];
  const void* W[4]; u16* WT[4]; int WM[4];
  const void* dw[3]; const void* da[3]; int dm[3];
  float* cvals;
  const u16* xb;
  const int* ei;
  int* histM;
};
__global__ __launch_bounds__(256) void k_setup(SetupArgs a) {
  __shared__ int h[NBKP];
  int b = blockIdx.x, t = threadIdx.x;
  if (b >= SETB) {  // ---- ehist part: 1564 blocks x 1024 edges ----
    int blk = b - SETB;
    int m_ = wave_mdetect(a.ei);
    for (int j = t; j < NBKP; j += 256) h[j] = 0;
    __syncthreads();
#pragma unroll
    for (int j = 0; j < 4; ++j) {
      int e = blk * 1024 + j * 256 + t;
      if (e < EE) {
        int d = m_ ? a.ei[2 * (size_t)(EE + e)] : a.ei[EE + e];
        d = clampi(d, NN);
        atomicAdd(&h[d >> 7], 1);
      }
    }
    __syncthreads();
    for (int j = t; j < NBKP; j += 256) a.histM[j * NBLK2P + blk] = h[j];
    return;
  }
  if (b < 12) {  // small-vector conversions
    int fl = wave_fdetect(a.xb);
    const void* src = a.cvt[b].src; u16* dst = a.cvt[b].dst; int n = a.cvt[b].n;
    for (int i = t; i < n; i += 256)
      dst[i] = fl ? f2bf(((const float*)src)[i]) : ((const u16*)src)[i];
    return;
  }
  b -= 12;
  if (b < 192) {  // weight transposes
    int fl = wave_fdetect(a.xb);
    int wsel, lb;
    if (b < 64)       { wsel = 0; lb = b; }
    else if (b < 128) { wsel = 1; lb = b - 64; }
    else if (b < 160) { wsel = 2; lb = b - 128; }
    else              { wsel = 3; lb = b - 160; }
    int M = a.WM[wsel];
    int i = lb * 256 + t;
    if (i < 128 * M) {
      int k = i / M, m = i % M;
      a.WT[wsel][m * 128 + k] = f2bf(ldf(a.W[wsel], i, fl));
    }
    return;
  }
  b -= 192;
  if (b < 3) {  // c = dot(We[0,:], a_e)
    if (t < 64) {
      int fl = wave_fdetect(a.xb);
      float s = 0.f; int m = a.dm[b];
      for (int j = t; j < m; j += 64) s += ldf(a.dw[b], j, fl) * ldf(a.da[b], j, fl);
      for (int off = 32; off; off >>= 1) s += __shfl_xor(s, off);
      if (t == 0) a.cvals[b] = s;
    }
    return;
  }
}

// ---------- per-bucket exclusive prefix over 1564 block-cols (carry loop) ----------
__global__ __launch_bounds__(512) void k_scanA(int* __restrict__ histM,
                                               int* __restrict__ binTot) {
  __shared__ int wt[8];
  __shared__ int carrySh;
  int b = blockIdx.x, t = threadIdx.x;
  if (t == 0) carrySh = 0;
  __syncthreads();
#pragma unroll
  for (int half = 0; half < 4; ++half) {
    int col = half * 512 + t;
    int v = (col < NBLK2) ? histM[b * NBLK2P + col] : 0;
    int lane = t & 63, w = t >> 6;
    int sc = v;
    for (int off = 1; off < 64; off <<= 1) {
      int o = __shfl_up(sc, off); if (lane >= off) sc += o;
    }
    if (lane == 63) wt[w] = sc;
    __syncthreads();
    int add = 0;
    for (int k = 0; k < w; ++k) add += wt[k];
    int excl = carrySh + add + sc - v;
    if (col < NBLK2) histM[b * NBLK2P + col] = excl;
    __syncthreads();
    if (t == 511) carrySh = excl + v;
    __syncthreads();
  }
  if (t == 0) binTot[b] = carrySh;
}

// ---------- exclusive scan of bucket totals -> bucketBase ----------
__global__ __launch_bounds__(256) void k_scanB(const int* __restrict__ binTot,
                                               int* __restrict__ bucketBase,
                                               int* __restrict__ row_off) {
  int t = threadIdx.x;
  int v[4]; int s = 0;
#pragma unroll
  for (int j = 0; j < 4; ++j) {
    int idx = t * 4 + j;
    v[j] = (idx < NBK) ? binTot[idx] : 0;
    s += v[j];
  }
  int lane = t & 63, w = t >> 6;
  int sc = s;
  for (int off = 1; off < 64; off <<= 1) {
    int o = __shfl_up(sc, off); if (lane >= off) sc += o;
  }
  __shared__ int wt[4];
  if (lane == 63) wt[w] = sc;
  __syncthreads();
  int add = 0;
  for (int k = 0; k < w; ++k) add += wt[k];
  int ex = add + sc - s;
#pragma unroll
  for (int j = 0; j < 4; ++j) {
    int idx = t * 4 + j;
    if (idx <= NBK) bucketBase[idx] = ex;
    ex += v[j];
  }
  if (t == 0) row_off[NN] = EE;
}

// ---------- GEMM body ----------
template<bool DUAL>
__device__ __forceinline__ void gemm_body(
    int bid, int fl, const void* __restrict__ Araw,
    const u16* __restrict__ WT,
    const u16* __restrict__ avs, const u16* __restrict__ avd,
    u16* __restrict__ xl,
    float* __restrict__ asrc, float* __restrict__ adst,
    float2* __restrict__ asAB, float* __restrict__ adstB, int n) {
  const int K = 128;
  int lane = threadIdx.x & 63;
  int wave = threadIdx.x >> 6;
  int quad = lane >> 4;
  int l16 = lane & 15;
  int r0 = (bid * 4 + wave) * 16;
  if (r0 >= n) return;
  int arow = r0 + l16; if (arow >= n) arow = n - 1;
  bf16x8 afr[4];
  if (fl) {
    const float* af = (const float*)Araw + (size_t)arow * K + quad * 8;
#pragma unroll
    for (int kb = 0; kb < 4; ++kb) {
      float4 f0 = *(const float4*)(af + kb * 32);
      float4 f1 = *(const float4*)(af + kb * 32 + 4);
      union { bf16x8 v; u16 s[8]; } t;
      t.s[0] = f2bf(f0.x); t.s[1] = f2bf(f0.y); t.s[2] = f2bf(f0.z); t.s[3] = f2bf(f0.w);
      t.s[4] = f2bf(f1.x); t.s[5] = f2bf(f1.y); t.s[6] = f2bf(f1.z); t.s[7] = f2bf(f1.w);
      afr[kb] = t.v;
    }
  } else {
    const u16* ab = (const u16*)Araw + (size_t)arow * K + quad * 8;
#pragma unroll
    for (int kb = 0; kb < 4; ++kb) afr[kb] = *(const bf16x8*)(ab + kb * 32);
  }
  f32x4 acc[8];
#pragma unroll
  for (int nb = 0; nb < 8; ++nb) acc[nb] = (f32x4){0.f, 0.f, 0.f, 0.f};
#pragma unroll
  for (int nb = 0; nb < 8; ++nb) {
    const u16* bbase = WT + (size_t)(nb * 16 + l16) * K + quad * 8;
#pragma unroll
    for (int kb = 0; kb < 4; ++kb) {
      bf16x8 bfr = *(const bf16x8*)(bbase + kb * 32);
      acc[nb] = __builtin_amdgcn_mfma_f32_16x16x32_bf16(afr[kb], bfr, acc[nb], 0, 0, 0);
    }
  }
  float ps[2][4] = {{0,0,0,0},{0,0,0,0}}, pd[2][4] = {{0,0,0,0},{0,0,0,0}};
#pragma unroll
  for (int nb = 0; nb < 8; ++nb) {
    const int g = (DUAL && nb >= 4) ? 1 : 0;
    int col = nb * 16 + l16;
    float vs = bf2f(avs[col]), vd = bf2f(avd[col]);
#pragma unroll
    for (int r = 0; r < 4; ++r) {
      int row = r0 + quad * 4 + r;
      float v = acc[nb][r];
      if (row < n) xl[(size_t)row * 128 + col] = f2bf(v);
      ps[g][r] += v * vs;
      pd[g][r] += v * vd;
    }
  }
#pragma unroll
  for (int off = 1; off < 16; off <<= 1) {
#pragma unroll
    for (int r = 0; r < 4; ++r) {
      ps[0][r] += __shfl_xor(ps[0][r], off);
      pd[0][r] += __shfl_xor(pd[0][r], off);
      if (DUAL) {
        ps[1][r] += __shfl_xor(ps[1][r], off);
        pd[1][r] += __shfl_xor(pd[1][r], off);
      }
    }
  }
  if (l16 == 0) {
#pragma unroll
    for (int r = 0; r < 4; ++r) {
      int row = r0 + quad * 4 + r;
      if (row < n) {
        if (DUAL) {
          asAB[row] = make_float2(ps[0][r], ps[1][r]);
          adst[row] = pd[0][r]; adstB[row] = pd[1][r];
        } else {
          asrc[row] = ps[0][r]; adst[row] = pd[0][r];
        }
      }
    }
  }
}

// ---------- MERGED: fine bucket scatter (1564 blocks) + layer-0 GEMM ----------
__global__ __launch_bounds__(256) void k_esgemm(
    const int* __restrict__ ei, const void* __restrict__ ew,
    const u16* __restrict__ xb, const int* __restrict__ histM,
    const int* __restrict__ bucketBase, int2* __restrict__ stage,
    const void* __restrict__ Araw, const u16* __restrict__ WT,
    const u16* __restrict__ avs, const u16* __restrict__ avd,
    u16* __restrict__ xl, float* __restrict__ asrc, float* __restrict__ adst, int n) {
  __shared__ int lbase[NBKP];
  __shared__ int cur[NBKP];
  if ((int)blockIdx.x >= NBLK2) {  // ---- gemm0 part ----
    int fl = wave_fdetect(xb);
    gemm_body<false>((int)blockIdx.x - NBLK2, fl, Araw, WT, avs, avd,
                     xl, asrc, adst, nullptr, nullptr, n);
    return;
  }
  // ---- escatter part: 1024 edges/block ----
  int blk = blockIdx.x, t = threadIdx.x;
  int m_ = wave_mdetect(ei);
  int fl = wave_fdetect(xb);
  for (int j = t; j < NBKP; j += 256) {
    int bb = (j < NBK) ? (bucketBase[j] + histM[j * NBLK2P + blk]) : 0;
    lbase[j] = bb; cur[j] = 0;
  }
  __syncthreads();
#pragma unroll
  for (int j = 0; j < 4; ++j) {
    int e = blk * 1024 + j * 256 + t;
    if (e < EE) {
      int s = m_ ? ei[2 * (size_t)e] : ei[e];
      int d = m_ ? ei[2 * (size_t)(EE + e)] : ei[EE + e];
      s = clampi(s, NN);
      d = clampi(d, NN);
      int bin = d >> 7, low = d & 127;
      int r = atomicAdd(&cur[bin], 1);
      int pos = lbase[bin] + r;
      if (pos >= 0 && pos < EE)
        stage[pos] = make_int2(s, (low << 16) | (int)f2bf(ldf(ew, e, fl)));
    }
  }
}

// ---------- per-bucket counting sort by low7 -> final CSR + row_off + la ----------
__global__ __launch_bounds__(256) void k_bucket(
    const int2* __restrict__ stage, const int* __restrict__ bucketBase,
    int2* __restrict__ edges, int* __restrict__ row_off, float* __restrict__ la) {
  __shared__ int hist[128];
  __shared__ float wsum[128];
  __shared__ int pref[128];
  __shared__ int cur[128];
  int b = blockIdx.x, t = threadIdx.x;
  int base = bucketBase[b], n = bucketBase[b + 1] - base;
  if (t < 128) { hist[t] = 0; wsum[t] = 0.f; cur[t] = 0; }
  __syncthreads();
  for (int i = t; i < n; i += 256) {
    int2 it = stage[base + i];
    int bin = (it.y >> 16) & 127;
    atomicAdd(&hist[bin], 1);
    atomicAdd(&wsum[bin], bf2f((u16)(it.y & 0xffff)));
  }
  __syncthreads();
  if (t == 0) {
    int run = 0;
    for (int j = 0; j < 128; ++j) { pref[j] = run; run += hist[j]; }
  }
  __syncthreads();
  if (t < 128) {
    int d = b * 128 + t;
    if (d < NN) {
      row_off[d] = base + pref[t];
      la[d] = hist[t] ? wsum[t] / (float)hist[t] : 0.f;
    }
  }
  for (int i = t; i < n; i += 256) {
    int2 it = stage[base + i];
    int bin = (it.y >> 16) & 127;
    int r = atomicAdd(&cur[bin], 1);
    edges[base + pref[bin] + r] = it;
  }
}

// ---------- standalone GEMM (bf16 A) ----------
template<bool DUAL>
__global__ __launch_bounds__(256) void k_gemm(
    const u16* __restrict__ A, const u16* __restrict__ WT,
    const u16* __restrict__ avs, const u16* __restrict__ avd,
    u16* __restrict__ xl, float* __restrict__ asrc, float* __restrict__ adst,
    float2* __restrict__ asAB, float* __restrict__ adstB, int n) {
  gemm_body<DUAL>(blockIdx.x, 0, A, WT, avs, avd, xl, asrc, adst, asAB, adstB, n);
}

// ---------- FUSED softmax+aggregation, 16 lanes/node, unroll-4 int4 gathers ----------
__global__ __launch_bounds__(256) void k_agg(
    const int* __restrict__ row_off, const int2* __restrict__ edges,
    const float* __restrict__ asrc, const float* __restrict__ adst,
    const float* __restrict__ la, const float* __restrict__ cptr,
    const u16* __restrict__ xl, const u16* __restrict__ bias,
    u16* __restrict__ out, int n) {
  __shared__ float lp[16][16];
  __shared__ int lsv[16][16];
  int tid = blockIdx.x * 256 + threadIdx.x;
  int d = tid >> 4;
  if (d >= n) return;
  int l = threadIdx.x & 15;
  int grp = threadIdx.x >> 4;
  float c = cptr[0];
  float ad = adst[d];
  float aL = lrelu(asrc[d] + ad + c * la[d]);
  float lsum = 0.f;
  int4 su = *(const int4*)(xl + (size_t)d * 128 + l * 8);
  float A0 = lo_f(su.x), A1 = hi_f(su.x), A2 = lo_f(su.y), A3 = hi_f(su.y);
  float A4 = lo_f(su.z), A5 = hi_f(su.z), A6 = lo_f(su.w), A7 = hi_f(su.w);
  float B0 = 0.f, B1 = 0.f, B2 = 0.f, B3 = 0.f, B4 = 0.f, B5 = 0.f, B6 = 0.f, B7 = 0.f;
  int beg = row_off[d], end = row_off[d + 1];
  for (int base = beg; base < end; base += 16) {
    int i = base + l;
    bool v = i < end;
    int2 ev = v ? edges[i] : make_int2(0, 0);
    float e = 0.f;
    if (v) e = __expf(lrelu(asrc[ev.x] + ad + c * bf2f((u16)(ev.y & 0xffff))) - aL);
    lsum += e;
    lp[grp][l] = e; lsv[grp][l] = ev.x;
    int cnt = end - base; if (cnt > 16) cnt = 16;
    int j = 0;
    for (; j + 4 <= cnt; j += 4) {
      float p0 = lp[grp][j + 0]; int s0 = lsv[grp][j + 0];
      float p1 = lp[grp][j + 1]; int s1 = lsv[grp][j + 1];
      float p2 = lp[grp][j + 2]; int s2 = lsv[grp][j + 2];
      float p3 = lp[grp][j + 3]; int s3 = lsv[grp][j + 3];
      int4 u0 = *(const int4*)(xl + (size_t)s0 * 128 + l * 8);
      int4 u1 = *(const int4*)(xl + (size_t)s1 * 128 + l * 8);
      int4 u2 = *(const int4*)(xl + (size_t)s2 * 128 + l * 8);
      int4 u3 = *(const int4*)(xl + (size_t)s3 * 128 + l * 8);
      A0 = fmaf(p0, lo_f(u0.x), A0); A1 = fmaf(p0, hi_f(u0.x), A1);
      A2 = fmaf(p0, lo_f(u0.y), A2); A3 = fmaf(p0, hi_f(u0.y), A3);
      A4 = fmaf(p0, lo_f(u0.z), A4); A5 = fmaf(p0, hi_f(u0.z), A5);
      A6 = fmaf(p0, lo_f(u0.w), A6); A7 = fmaf(p0, hi_f(u0.w), A7);
      B0 = fmaf(p1, lo_f(u1.x), B0); B1 = fmaf(p1, hi_f(u1.x), B1);
      B2 = fmaf(p1, lo_f(u1.y), B2); B3 = fmaf(p1, hi_f(u1.y), B3);
      B4 = fmaf(p1, lo_f(u1.z), B4); B5 = fmaf(p1, hi_f(u1.z), B5);
      B6 = fmaf(p1, lo_f(u1.w), B6); B7 = fmaf(p1, hi_f(u1.w), B7);
      A0 = fmaf(p2, lo_f(u2.x), A0); A1 = fmaf(p2, hi_f(u2.x), A1);
      A2 = fmaf(p2, lo_f(u2.y), A2); A3 = fmaf(p2, hi_f(u2.y), A3);
      A4 = fmaf(p2, lo_f(u2.z), A4); A5 = fmaf(p2, hi_f(u2.z), A5);
      A6 = fmaf(p2, lo_f(u2.w), A6); A7 = fmaf(p2, hi_f(u2.w), A7);
      B0 = fmaf(p3, lo_f(u3.x), B0); B1 = fmaf(p3, hi_f(u3.x), B1);
      B2 = fmaf(p3, lo_f(u3.y), B2); B3 = fmaf(p3, hi_f(u3.y), B3);
      B4 = fmaf(p3, lo_f(u3.z), B4); B5 = fmaf(p3, hi_f(u3.z), B5);
      B6 = fmaf(p3, lo_f(u3.w), B6); B7 = fmaf(p3, hi_f(u3.w), B7);
    }
    for (; j + 2 <= cnt; j += 2) {
      float p0 = lp[grp][j];     int s0 = lsv[grp][j];
      float p1 = lp[grp][j + 1]; int s1 = lsv[grp][j + 1];
      int4 u0 = *(const int4*)(xl + (size_t)s0 * 128 + l * 8);
      int4 u1 = *(const int4*)(xl + (size_t)s1 * 128 + l * 8);
      A0 = fmaf(p0, lo_f(u0.x), A0); A1 = fmaf(p0, hi_f(u0.x), A1);
      A2 = fmaf(p0, lo_f(u0.y), A2); A3 = fmaf(p0, hi_f(u0.y), A3);
      A4 = fmaf(p0, lo_f(u0.z), A4); A5 = fmaf(p0, hi_f(u0.z), A5);
      A6 = fmaf(p0, lo_f(u0.w), A6); A7 = fmaf(p0, hi_f(u0.w), A7);
      B0 = fmaf(p1, lo_f(u1.x), B0); B1 = fmaf(p1, hi_f(u1.x), B1);
      B2 = fmaf(p1, lo_f(u1.y), B2); B3 = fmaf(p1, hi_f(u1.y), B3);
      B4 = fmaf(p1, lo_f(u1.z), B4); B5 = fmaf(p1, hi_f(u1.z), B5);
      B6 = fmaf(p1, lo_f(u1.w), B6); B7 = fmaf(p1, hi_f(u1.w), B7);
    }
    if (j < cnt) {
      float p0 = lp[grp][j]; int s0 = lsv[grp][j];
      int4 u0 = *(const int4*)(xl + (size_t)s0 * 128 + l * 8);
      A0 = fmaf(p0, lo_f(u0.x), A0); A1 = fmaf(p0, hi_f(u0.x), A1);
      A2 = fmaf(p0, lo_f(u0.y), A2); A3 = fmaf(p0, hi_f(u0.y), A3);
      A4 = fmaf(p0, lo_f(u0.z), A4); A5 = fmaf(p0, hi_f(u0.z), A5);
      A6 = fmaf(p0, lo_f(u0.w), A6); A7 = fmaf(p0, hi_f(u0.w), A7);
    }
  }
  A0 += B0; A1 += B1; A2 += B2; A3 += B3; A4 += B4; A5 += B5; A6 += B6; A7 += B7;
#pragma unroll
  for (int off = 1; off < 16; off <<= 1) lsum += __shfl_xor(lsum, off);
  float inv = 1.f / (lsum + 1.f);
  int4 bv = *(const int4*)(bias + l * 8);
  float o0 = fmaxf(fmaf(A0, inv, lo_f((unsigned)bv.x)), 0.f);
  float o1 = fmaxf(fmaf(A1, inv, hi_f((unsigned)bv.x)), 0.f);
  float o2 = fmaxf(fmaf(A2, inv, lo_f((unsigned)bv.y)), 0.f);
  float o3 = fmaxf(fmaf(A3, inv, hi_f((unsigned)bv.y)), 0.f);
  float o4 = fmaxf(fmaf(A4, inv, lo_f((unsigned)bv.z)), 0.f);
  float o5 = fmaxf(fmaf(A5, inv, hi_f((unsigned)bv.z)), 0.f);
  float o6 = fmaxf(fmaf(A6, inv, lo_f((unsigned)bv.w)), 0.f);
  float o7 = fmaxf(fmaf(A7, inv, hi_f((unsigned)bv.w)), 0.f);
  int4 ov;
  ov.x = (int)pack2(o0, o1); ov.y = (int)pack2(o2, o3);
  ov.z = (int)pack2(o4, o5); ov.w = (int)pack2(o6, o7);
  *(int4*)(out + (size_t)d * 128 + l * 8) = ov;
}

// ---------- FUSED dual-head, 16 lanes/node, unroll-4: lanes 0-7 mu, 8-15 logstd ----------
__global__ __launch_bounds__(256) void k_aggh(
    const int* __restrict__ row_off, const int2* __restrict__ edges,
    const float2* __restrict__ asAB, const float* __restrict__ adA,
    const float* __restrict__ adB,
    const float* __restrict__ la, const float* __restrict__ cptr,
    const u16* __restrict__ xl, const u16* __restrict__ bias,
    float* __restrict__ outf, int n) {
  __shared__ float lpA[16][16];
  __shared__ float lpB[16][16];
  __shared__ int lsv[16][16];
  int tid = blockIdx.x * 256 + threadIdx.x;
  int d = tid >> 4;
  if (d >= n) return;
  int l = threadIdx.x & 15;
  int grp = threadIdx.x >> 4;
  bool isMu = l < 8;
  float c = cptr[0];
  float adAd = adA[d], adBd = adB[d];
  float2 abd = asAB[d];
  float aLA = lrelu(abd.x + adAd + c * la[d]);
  float aLB = lrelu(abd.y + adBd);
  float lsA = 0.f, lsB = 0.f;
  int4 su = *(const int4*)(xl + (size_t)d * 128 + l * 8);
  float A0 = lo_f(su.x), A1 = hi_f(su.x), A2 = lo_f(su.y), A3 = hi_f(su.y);
  float A4 = lo_f(su.z), A5 = hi_f(su.z), A6 = lo_f(su.w), A7 = hi_f(su.w);
  float B0 = 0.f, B1 = 0.f, B2 = 0.f, B3 = 0.f, B4 = 0.f, B5 = 0.f, B6 = 0.f, B7 = 0.f;
  int beg = row_off[d], end = row_off[d + 1];
  for (int base = beg; base < end; base += 16) {
    int i = base + l;
    bool v = i < end;
    int2 ev = v ? edges[i] : make_int2(0, 0);
    float eA = 0.f, eB = 0.f;
    if (v) {
      float2 ab = asAB[ev.x];
      eA = __expf(lrelu(ab.x + adAd + c * bf2f((u16)(ev.y & 0xffff))) - aLA);
      eB = __expf(lrelu(ab.y + adBd) - aLB);
    }
    lsA += eA; lsB += eB;
    lpA[grp][l] = eA; lpB[grp][l] = eB; lsv[grp][l] = ev.x;
    const float* lpp = isMu ? lpA[grp] : lpB[grp];
    int cnt = end - base; if (cnt > 16) cnt = 16;
    int j = 0;
    for (; j + 4 <= cnt; j += 4) {
      float p0 = lpp[j + 0]; int s0 = lsv[grp][j + 0];
      float p1 = lpp[j + 1]; int s1 = lsv[grp][j + 1];
      float p2 = lpp[j + 2]; int s2 = lsv[grp][j + 2];
      float p3 = lpp[j + 3]; int s3 = lsv[grp][j + 3];
      int4 u0 = *(const int4*)(xl + (size_t)s0 * 128 + l * 8);
      int4 u1 = *(const int4*)(xl + (size_t)s1 * 128 + l * 8);
      int4 u2 = *(const int4*)(xl + (size_t)s2 * 128 + l * 8);
      int4 u3 = *(const int4*)(xl + (size_t)s3 * 128 + l * 8);
      A0 = fmaf(p0, lo_f(u0.x), A0); A1 = fmaf(p0, hi_f(u0.x), A1);
      A2 = fmaf(p0, lo_f(u0.y), A2); A3 = fmaf(p0, hi_f(u0.y), A3);
      A4 = fmaf(p0, lo_f(u0.z), A4); A5 = fmaf(p0, hi_f(u0.z), A5);
      A6 = fmaf(p0, lo_f(u0.w), A6); A7 = fmaf(p0, hi_f(u0.w), A7);
      B0 = fmaf(p1, lo_f(u1.x), B0); B1 = fmaf(p1, hi_f(u1.x), B1);
      B2 = fmaf(p1, lo_f(u1.y), B2); B3 = fmaf(p1, hi_f(u1.y), B3);
      B4 = fmaf(p1, lo_f(u1.z), B4); B5 = fmaf(p1, hi_f(u1.z), B5);
      B6 = fmaf(p1, lo_f(u1.w), B6); B7 = fmaf(p1, hi_f(u1.w), B7);
      A0 = fmaf(p2, lo_f(u2.x), A0); A1 = fmaf(p2, hi_f(u2.x), A1);
      A2 = fmaf(p2, lo_f(u2.y), A2); A3 = fmaf(p2, hi_f(u2.y), A3);
      A4 = fmaf(p2, lo_f(u2.z), A4); A5 = fmaf(p2, hi_f(u2.z), A5);
      A6 = fmaf(p2, lo_f(u2.w), A6); A7 = fmaf(p2, hi_f(u2.w), A7);
      B0 = fmaf(p3, lo_f(u3.x), B0); B1 = fmaf(p3, hi_f(u3.x), B1);
      B2 = fmaf(p3, lo_f(u3.y), B2); B3 = fmaf(p3, hi_f(u3.y), B3);
      B4 = fmaf(p3, lo_f(u3.z), B4); B5 = fmaf(p3, hi_f(u3.z), B5);
      B6 = fmaf(p3, lo_f(u3.w), B6); B7 = fmaf(p3, hi_f(u3.w), B7);
    }
    for (; j + 2 <= cnt; j += 2) {
      float p0 = lpp[j];     int s0 = lsv[grp][j];
      float p1 = lpp[j + 1]; int s1 = lsv[grp][j + 1];
      int4 u0 = *(const int4*)(xl + (size_t)s0 * 128 + l * 8);
      int4 u1 = *(const int4*)(xl + (size_t)s1 * 128 + l * 8);
      A0 = fmaf(p0, lo_f(u0.x), A0); A1 = fmaf(p0, hi_f(u0.x), A1);
      A2 = fmaf(p0, lo_f(u0.y), A2); A3 = fmaf(p0, hi_f(u0.y), A3);
      A4 = fmaf(p0, lo_f(u0.z), A4); A5 = fmaf(p0, hi_f(u0.z), A5);
      A6 = fmaf(p0, lo_f(u0.w), A6); A7 = fmaf(p0, hi_f(u0.w), A7);
      B0 = fmaf(p1, lo_f(u1.x), B0); B1 = fmaf(p1, hi_f(u1.x), B1);
      B2 = fmaf(p1, lo_f(u1.y), B2); B3 = fmaf(p1, hi_f(u1.y), B3);
      B4 = fmaf(p1, lo_f(u1.z), B4); B5 = fmaf(p1, hi_f(u1.z), B5);
      B6 = fmaf(p1, lo_f(u1.w), B6); B7 = fmaf(p1, hi_f(u1.w), B7);
    }
    if (j < cnt) {
      float p0 = lpp[j]; int s0 = lsv[grp][j];
      int4 u0 = *(const int4*)(xl + (size_t)s0 * 128 + l * 8);
      A0 = fmaf(p0, lo_f(u0.x), A0); A1 = fmaf(p0, hi_f(u0.x), A1);
      A2 = fmaf(p0, lo_f(u0.y), A2); A3 = fmaf(p0, hi_f(u0.y), A3);
      A4 = fmaf(p0, lo_f(u0.z), A4); A5 = fmaf(p0, hi_f(u0.z), A5);
      A6 = fmaf(p0, lo_f(u0.w), A6); A7 = fmaf(p0, hi_f(u0.w), A7);
    }
  }
  A0 += B0; A1 += B1; A2 += B2; A3 += B3; A4 += B4; A5 += B5; A6 += B6; A7 += B7;
#pragma unroll
  for (int off = 1; off < 16; off <<= 1) {
    lsA += __shfl_xor(lsA, off);
    lsB += __shfl_xor(lsB, off);
  }
  float inv = 1.f / ((isMu ? lsA : lsB) + 1.f);
  int4 bv = *(const int4*)(bias + l * 8);
  float4 oa, ob;
  oa.x = fmaf(A0, inv, lo_f((unsigned)bv.x));
  oa.y = fmaf(A1, inv, hi_f((unsigned)bv.x));
  oa.z = fmaf(A2, inv, lo_f((unsigned)bv.y));
  oa.w = fmaf(A3, inv, hi_f((unsigned)bv.y));
  ob.x = fmaf(A4, inv, lo_f((unsigned)bv.z));
  ob.y = fmaf(A5, inv, hi_f((unsigned)bv.z));
  ob.z = fmaf(A6, inv, lo_f((unsigned)bv.w));
  ob.w = fmaf(A7, inv, hi_f((unsigned)bv.w));
  float* obase = isMu ? (outf + (size_t)d * 64 + l * 8)
                      : (outf + (size_t)NN * 64 + (size_t)d * 64 + (l - 8) * 8);
  *(float4*)obase = oa;
  *(float4*)(obase + 4) = ob;
}

extern "C" void kernel_launch(void* const* d_in, const int* in_sizes, int n_in,
                              void* d_out, int out_size, void* d_ws, size_t ws_size,
                              hipStream_t stream) {
  (void)in_sizes; (void)n_in;
  const int* ei = (const int*)d_in[1];
  const u16* xb = (const u16*)d_in[0];
  float* outf = (float*)d_out;  // fp32 output

  // d_out scratch (dead before its region is written as output):
  //   histM: [0 .. 4.92MB)    consumed by k_esgemm/scanA (before agg L1 -> h1 @[0,25.6MB))
  //   stage: [5MB .. 17.8MB)  consumed by k_bucket (ditto)
  u16* regionA = (u16*)d_out;                     // h1 (agg L1 output)
  u16* regionB = (u16*)d_out + (size_t)NN * 128;  // h0 (agg L0 output)
  int* histM = (int*)d_out;                       // [NBKP][NBLK2P] = 4.92 MB
  int2* stage = (int2*)((char*)d_out + (size_t)5 * 1024 * 1024);

  char* p = (char*)d_ws;
  auto alloc = [&](size_t bytes) -> char* {
    char* r = p; p += (bytes + 255) & ~(size_t)255; return r;
  };
  int*   row_off   = (int*)alloc((NN + 1) * 4);
  int*   binTot    = (int*)alloc(NBKP * 4);
  int*   bucketBase= (int*)alloc((NBKP + 2) * 4);
  float* la        = (float*)alloc(NN * 4);
  float* asrcA     = (float*)alloc(NN * 4);
  float* adstA     = (float*)alloc(NN * 4);
  float* adstB     = (float*)alloc(NN * 4);
  float2* asAB     = (float2*)alloc((size_t)NN * 8);
  int2*  edges     = (int2*)alloc((size_t)EE * 8);
  u16*   WT0       = (u16*)alloc(128 * 128 * 2);
  u16*   WT1       = (u16*)alloc(128 * 128 * 2);
  u16*   WTh       = (u16*)alloc(128 * 128 * 2);
  float* cvals     = (float*)alloc(16);
  u16*   vecc      = (u16*)alloc(9 * 256);
  u16*   xl        = (u16*)alloc((size_t)NN * 128 * 2);  // 25.6 MB

  size_t NEED = (size_t)(p - (char*)d_ws);  // ~41.3 MB
  if (ws_size < NEED) {
    k_fillf<<<(out_size + 255) / 256, 256, 0, stream>>>(outf, out_size, 0.125f);
    return;
  }

  u16* as0c = vecc + 0 * 128; u16* ad0c = vecc + 1 * 128; u16* b0c = vecc + 2 * 128;
  u16* as1c = vecc + 3 * 128; u16* ad1c = vecc + 4 * 128; u16* b1c = vecc + 5 * 128;
  u16* hvs  = vecc + 6 * 128; u16* hvd  = vecc + 7 * 128; u16* bh  = vecc + 8 * 128;

  // ---- fused setup + fine ehist ----
  SetupArgs sa;
  sa.cvt[0]  = {d_in[4],  as0c, 128};
  sa.cvt[1]  = {d_in[5],  ad0c, 128};
  sa.cvt[2]  = {d_in[8],  b0c,  128};
  sa.cvt[3]  = {d_in[10], as1c, 128};
  sa.cvt[4]  = {d_in[11], ad1c, 128};
  sa.cvt[5]  = {d_in[14], b1c,  128};
  sa.cvt[6]  = {d_in[16], hvs,      64};  // asm
  sa.cvt[7]  = {d_in[22], hvs + 64, 64};  // asl
  sa.cvt[8]  = {d_in[17], hvd,      64};  // adm
  sa.cvt[9]  = {d_in[23], hvd + 64, 64};  // adl
  sa.cvt[10] = {d_in[20], bh,       64};  // bm
  sa.cvt[11] = {d_in[24], bh + 64,  64};  // bl
  sa.W[0] = d_in[3];  sa.WT[0] = WT0;            sa.WM[0] = 128;
  sa.W[1] = d_in[9];  sa.WT[1] = WT1;            sa.WM[1] = 128;
  sa.W[2] = d_in[15]; sa.WT[2] = WTh;            sa.WM[2] = 64;
  sa.W[3] = d_in[21]; sa.WT[3] = WTh + 64 * 128; sa.WM[3] = 64;
  sa.dw[0] = d_in[7];  sa.da[0] = d_in[6];  sa.dm[0] = 128;
  sa.dw[1] = d_in[13]; sa.da[1] = d_in[12]; sa.dm[1] = 128;
  sa.dw[2] = d_in[19]; sa.da[2] = d_in[18]; sa.dm[2] = 64;
  sa.cvals = cvals; sa.xb = xb; sa.ei = ei; sa.histM = histM;
  k_setup<<<SETB + NBLK2, 256, 0, stream>>>(sa);

  const int gblocks = (((NN + 15) / 16) + 3) / 4;
  const int eblocks16 = (int)(((size_t)NN * 16 + 255) / 256);

  // ---- CSR offsets ----
  k_scanA<<<NBK, 512, 0, stream>>>(histM, binTot);
  k_scanB<<<1, 256, 0, stream>>>(binTot, bucketBase, row_off);
  // ---- fine bucket scatter (1564 blocks) co-resident with layer-0 GEMM ----
  k_esgemm<<<NBLK2 + gblocks, 256, 0, stream>>>(ei, d_in[2], xb, histM, bucketBase,
                                                stage, d_in[0], WT0, as0c, ad0c,
                                                xl, asrcA, adstA, NN);
  k_bucket<<<NBK, 256, 0, stream>>>(stage, bucketBase, edges, row_off, la);

  // ---- layer 0 aggregation: xl -> h0(regionB) ----
  k_agg<<<eblocks16, 256, 0, stream>>>(row_off, edges, asrcA, adstA, la,
                                       cvals + 0, xl, b0c, regionB, NN);
  // ---- layer 1 ----
  k_gemm<false><<<gblocks, 256, 0, stream>>>(regionB, WT1, as1c, ad1c,
                                             xl, asrcA, adstA, nullptr, nullptr, NN);
  k_agg<<<eblocks16, 256, 0, stream>>>(row_off, edges, asrcA, adstA, la,
                                       cvals + 1, xl, b1c, regionA, NN);
  // ---- heads ----
  k_gemm<true><<<gblocks, 256, 0, stream>>>(regionA, WTh, hvs, hvd,
                                            xl, nullptr, adstA, asAB, adstB, NN);
  k_aggh<<<eblocks16, 256, 0, stream>>>(row_off, edges, asAB, adstA, adstB,
                                        la, cvals + 2, xl, bh, outf, NN);
}

// Round 11
// 512.252 us; speedup vs baseline: 1.0458x; 1.0213x over previous
//
#include <hip/hip_runtime.h>

#define NN 100000
#define EE 1600000
#define NBK 782          // coarse buckets = ceil(NN/128)
#define NBKP 784
#define NBLK 391         // edge blocks = ceil(EE/4096)
#define NBLKP 392
#define SETB 207         // setup blocks: 12 cvt + 192 transpose + 3 dots

typedef __attribute__((ext_vector_type(8))) __bf16 bf16x8;
typedef __attribute__((ext_vector_type(4))) float f32x4;
typedef unsigned short u16;

__device__ __forceinline__ float bf2f(u16 v) {
  union { unsigned u; float f; } x; x.u = ((unsigned)v) << 16; return x.f;
}
__device__ __forceinline__ u16 f2bf(float f) {
  union { unsigned u; float f; } x; x.f = f;
  x.u += 0x7fffu + ((x.u >> 16) & 1u);
  return (u16)(x.u >> 16);
}
__device__ __forceinline__ float lo_f(unsigned u) {
  union { unsigned u; float f; } x; x.u = u << 16; return x.f;
}
__device__ __forceinline__ float hi_f(unsigned u) {
  union { unsigned u; float f; } x; x.u = u & 0xffff0000u; return x.f;
}
__device__ __forceinline__ unsigned pack2(float a, float b) {
  return (unsigned)f2bf(a) | ((unsigned)f2bf(b) << 16);
}
__device__ __forceinline__ float lrelu(float x) { return x > 0.f ? x : 0.2f * x; }
__device__ __forceinline__ int clampi(int v, int hi) {
  return ((unsigned)v < (unsigned)hi) ? v : 0;
}
__device__ __forceinline__ float ldf(const void* p, size_t i, int fl) {
  return fl ? ((const float*)p)[i] : bf2f(((const u16*)p)[i]);
}

// ---- per-wave inline dtype detection ----
__device__ __forceinline__ int wave_fdetect(const u16* __restrict__ xb) {
  int lane = threadIdx.x & 63;
  int bad = 0;
#pragma unroll
  for (int j = 0; j < 4; ++j) {
    float a = fabsf(bf2f(xb[lane * 4 + j]));
    bad |= (!(a == a) || a > 1e6f) ? 1 : 0;
  }
  return (__ballot(bad) != 0ull) ? 1 : 0;
}
__device__ __forceinline__ int wave_mdetect(const int* __restrict__ ei) {
  int lane = threadIdx.x & 63;
  int v = (lane < 32) ? ei[2 * lane + 1] : 0;
  return (__ballot(v != 0) == 0ull) ? 1 : 0;
}

// ---------- sentinel fill ----------
__global__ void k_fillf(float* __restrict__ o, int n, float v) {
  int i = blockIdx.x * 256 + threadIdx.x;
  if (i < n) o[i] = v;
}

// ---------- fused setup (+ coarse edge histogram) ----------
struct CvtDesc { const void* src; u16* dst; int n; };
struct SetupArgs {
  CvtDesc cvt[12];
  const void* W[4]; u16* WT[4]; int WM[4];
  const void* dw[3]; const void* da[3]; int dm[3];
  float* cvals;
  const u16* xb;
  const int* ei;
  int* histM;
};
__global__ __launch_bounds__(256) void k_setup(SetupArgs a) {
  __shared__ int h[NBKP];
  int b = blockIdx.x, t = threadIdx.x;
  if (b >= SETB) {  // ---- ehist part: blocks [SETB, SETB+NBLK) ----
    int blk = b - SETB;
    int m_ = wave_mdetect(a.ei);
    for (int j = t; j < NBKP; j += 256) h[j] = 0;
    __syncthreads();
#pragma unroll
    for (int j = 0; j < 16; ++j) {
      int e = blk * 4096 + j * 256 + t;
      if (e < EE) {
        int d = m_ ? a.ei[2 * (size_t)(EE + e)] : a.ei[EE + e];
        d = clampi(d, NN);
        atomicAdd(&h[d >> 7], 1);
      }
    }
    __syncthreads();
    for (int j = t; j < NBKP; j += 256) a.histM[j * NBLKP + blk] = h[j];
    return;
  }
  if (b < 12) {  // small-vector conversions
    int fl = wave_fdetect(a.xb);
    const void* src = a.cvt[b].src; u16* dst = a.cvt[b].dst; int n = a.cvt[b].n;
    for (int i = t; i < n; i += 256)
      dst[i] = fl ? f2bf(((const float*)src)[i]) : ((const u16*)src)[i];
    return;
  }
  b -= 12;
  if (b < 192) {  // weight transposes: W0:64, W1:64, Wm:32, Wl:32 blocks
    int fl = wave_fdetect(a.xb);
    int wsel, lb;
    if (b < 64)       { wsel = 0; lb = b; }
    else if (b < 128) { wsel = 1; lb = b - 64; }
    else if (b < 160) { wsel = 2; lb = b - 128; }
    else              { wsel = 3; lb = b - 160; }
    int M = a.WM[wsel];
    int i = lb * 256 + t;
    if (i < 128 * M) {
      int k = i / M, m = i % M;
      a.WT[wsel][m * 128 + k] = f2bf(ldf(a.W[wsel], i, fl));
    }
    return;
  }
  b -= 192;
  if (b < 3) {  // c = dot(We[0,:], a_e)
    if (t < 64) {
      int fl = wave_fdetect(a.xb);
      float s = 0.f; int m = a.dm[b];
      for (int j = t; j < m; j += 64) s += ldf(a.dw[b], j, fl) * ldf(a.da[b], j, fl);
      for (int off = 32; off; off >>= 1) s += __shfl_xor(s, off);
      if (t == 0) a.cvals[b] = s;
    }
    return;
  }
}

// ---------- per-bucket exclusive prefix over blocks (in-place) + bucket totals ----------
__global__ __launch_bounds__(512) void k_scanA(int* __restrict__ histM,
                                               int* __restrict__ binTot) {
  int b = blockIdx.x, t = threadIdx.x;
  int v = (t < NBLK) ? histM[b * NBLKP + t] : 0;
  int lane = t & 63, w = t >> 6;
  int sc = v;
  for (int off = 1; off < 64; off <<= 1) {
    int o = __shfl_up(sc, off); if (lane >= off) sc += o;
  }
  __shared__ int wt[8];
  if (lane == 63) wt[w] = sc;
  __syncthreads();
  int add = 0;
  for (int k = 0; k < w; ++k) add += wt[k];
  int excl = sc - v + add;
  if (t < NBLK) histM[b * NBLKP + t] = excl;
  if (t == 511) binTot[b] = excl;  // v=0 here -> excl = total
}

// ---------- exclusive scan of bucket totals -> bucketBase ----------
__global__ __launch_bounds__(256) void k_scanB(const int* __restrict__ binTot,
                                               int* __restrict__ bucketBase,
                                               int* __restrict__ row_off) {
  int t = threadIdx.x;
  int v[4]; int s = 0;
#pragma unroll
  for (int j = 0; j < 4; ++j) {
    int idx = t * 4 + j;
    v[j] = (idx < NBK) ? binTot[idx] : 0;
    s += v[j];
  }
  int lane = t & 63, w = t >> 6;
  int sc = s;
  for (int off = 1; off < 64; off <<= 1) {
    int o = __shfl_up(sc, off); if (lane >= off) sc += o;
  }
  __shared__ int wt[4];
  if (lane == 63) wt[w] = sc;
  __syncthreads();
  int add = 0;
  for (int k = 0; k < w; ++k) add += wt[k];
  int ex = add + sc - s;
#pragma unroll
  for (int j = 0; j < 4; ++j) {
    int idx = t * 4 + j;
    if (idx <= NBK) bucketBase[idx] = ex;
    ex += v[j];
  }
  if (t == 0) row_off[NN] = EE;
}

// ---------- GEMM body: xl = A @ W + logit epilogues ----------
template<bool DUAL>
__device__ __forceinline__ void gemm_body(
    int bid, int fl, const void* __restrict__ Araw,
    const u16* __restrict__ WT,
    const u16* __restrict__ avs, const u16* __restrict__ avd,
    u16* __restrict__ xl,
    float* __restrict__ asrc, float* __restrict__ adst,
    float2* __restrict__ asAB, float* __restrict__ adstB, int n) {
  const int K = 128;
  int lane = threadIdx.x & 63;
  int wave = threadIdx.x >> 6;
  int quad = lane >> 4;
  int l16 = lane & 15;
  int r0 = (bid * 4 + wave) * 16;
  if (r0 >= n) return;
  int arow = r0 + l16; if (arow >= n) arow = n - 1;
  bf16x8 afr[4];
  if (fl) {
    const float* af = (const float*)Araw + (size_t)arow * K + quad * 8;
#pragma unroll
    for (int kb = 0; kb < 4; ++kb) {
      float4 f0 = *(const float4*)(af + kb * 32);
      float4 f1 = *(const float4*)(af + kb * 32 + 4);
      union { bf16x8 v; u16 s[8]; } t;
      t.s[0] = f2bf(f0.x); t.s[1] = f2bf(f0.y); t.s[2] = f2bf(f0.z); t.s[3] = f2bf(f0.w);
      t.s[4] = f2bf(f1.x); t.s[5] = f2bf(f1.y); t.s[6] = f2bf(f1.z); t.s[7] = f2bf(f1.w);
      afr[kb] = t.v;
    }
  } else {
    const u16* ab = (const u16*)Araw + (size_t)arow * K + quad * 8;
#pragma unroll
    for (int kb = 0; kb < 4; ++kb) afr[kb] = *(const bf16x8*)(ab + kb * 32);
  }
  f32x4 acc[8];
#pragma unroll
  for (int nb = 0; nb < 8; ++nb) acc[nb] = (f32x4){0.f, 0.f, 0.f, 0.f};
#pragma unroll
  for (int nb = 0; nb < 8; ++nb) {
    const u16* bbase = WT + (size_t)(nb * 16 + l16) * K + quad * 8;
#pragma unroll
    for (int kb = 0; kb < 4; ++kb) {
      bf16x8 bfr = *(const bf16x8*)(bbase + kb * 32);
      acc[nb] = __builtin_amdgcn_mfma_f32_16x16x32_bf16(afr[kb], bfr, acc[nb], 0, 0, 0);
    }
  }
  float ps[2][4] = {{0,0,0,0},{0,0,0,0}}, pd[2][4] = {{0,0,0,0},{0,0,0,0}};
#pragma unroll
  for (int nb = 0; nb < 8; ++nb) {
    const int g = (DUAL && nb >= 4) ? 1 : 0;
    int col = nb * 16 + l16;
    float vs = bf2f(avs[col]), vd = bf2f(avd[col]);
#pragma unroll
    for (int r = 0; r < 4; ++r) {
      int row = r0 + quad * 4 + r;
      float v = acc[nb][r];
      if (row < n) xl[(size_t)row * 128 + col] = f2bf(v);
      ps[g][r] += v * vs;
      pd[g][r] += v * vd;
    }
  }
#pragma unroll
  for (int off = 1; off < 16; off <<= 1) {
#pragma unroll
    for (int r = 0; r < 4; ++r) {
      ps[0][r] += __shfl_xor(ps[0][r], off);
      pd[0][r] += __shfl_xor(pd[0][r], off);
      if (DUAL) {
        ps[1][r] += __shfl_xor(ps[1][r], off);
        pd[1][r] += __shfl_xor(pd[1][r], off);
      }
    }
  }
  if (l16 == 0) {
#pragma unroll
    for (int r = 0; r < 4; ++r) {
      int row = r0 + quad * 4 + r;
      if (row < n) {
        if (DUAL) {
          asAB[row] = make_float2(ps[0][r], ps[1][r]);
          adst[row] = pd[0][r]; adstB[row] = pd[1][r];
        } else {
          asrc[row] = ps[0][r]; adst[row] = pd[0][r];
        }
      }
    }
  }
}

// ---------- MERGED: bucket scatter (LDS ranks) + layer-0 GEMM (independent) ----------
__global__ __launch_bounds__(256) void k_esgemm(
    const int* __restrict__ ei, const void* __restrict__ ew,
    const u16* __restrict__ xb, const int* __restrict__ histM,
    const int* __restrict__ bucketBase, int2* __restrict__ stage,
    const void* __restrict__ Araw, const u16* __restrict__ WT,
    const u16* __restrict__ avs, const u16* __restrict__ avd,
    u16* __restrict__ xl, float* __restrict__ asrc, float* __restrict__ adst, int n) {
  __shared__ int lbase[NBKP];
  __shared__ int cur[NBKP];
  if ((int)blockIdx.x >= NBLK) {  // ---- gemm0 part ----
    int fl = wave_fdetect(xb);
    gemm_body<false>((int)blockIdx.x - NBLK, fl, Araw, WT, avs, avd,
                     xl, asrc, adst, nullptr, nullptr, n);
    return;
  }
  // ---- escatter part ----
  int blk = blockIdx.x, t = threadIdx.x;
  int m_ = wave_mdetect(ei);
  int fl = wave_fdetect(xb);
  for (int j = t; j < NBKP; j += 256) {
    int bb = (j < NBK) ? (bucketBase[j] + histM[j * NBLKP + blk]) : 0;
    lbase[j] = bb; cur[j] = 0;
  }
  __syncthreads();
#pragma unroll
  for (int j = 0; j < 16; ++j) {
    int e = blk * 4096 + j * 256 + t;
    if (e < EE) {
      int s = m_ ? ei[2 * (size_t)e] : ei[e];
      int d = m_ ? ei[2 * (size_t)(EE + e)] : ei[EE + e];
      s = clampi(s, NN);
      d = clampi(d, NN);
      int bin = d >> 7, low = d & 127;
      int r = atomicAdd(&cur[bin], 1);
      int pos = lbase[bin] + r;
      if (pos >= 0 && pos < EE)
        stage[pos] = make_int2(s, (low << 16) | (int)f2bf(ldf(ew, e, fl)));
    }
  }
}

// ---------- per-bucket counting sort by low7 -> final CSR + row_off + la ----------
__global__ __launch_bounds__(256) void k_bucket(
    const int2* __restrict__ stage, const int* __restrict__ bucketBase,
    int2* __restrict__ edges, int* __restrict__ row_off, float* __restrict__ la) {
  __shared__ int hist[128];
  __shared__ float wsum[128];
  __shared__ int pref[128];
  __shared__ int cur[128];
  int b = blockIdx.x, t = threadIdx.x;
  int base = bucketBase[b], n = bucketBase[b + 1] - base;
  if (t < 128) { hist[t] = 0; wsum[t] = 0.f; cur[t] = 0; }
  __syncthreads();
  for (int i = t; i < n; i += 256) {
    int2 it = stage[base + i];
    int bin = (it.y >> 16) & 127;
    atomicAdd(&hist[bin], 1);
    atomicAdd(&wsum[bin], bf2f((u16)(it.y & 0xffff)));
  }
  __syncthreads();
  if (t == 0) {
    int run = 0;
    for (int j = 0; j < 128; ++j) { pref[j] = run; run += hist[j]; }
  }
  __syncthreads();
  if (t < 128) {
    int d = b * 128 + t;
    if (d < NN) {
      row_off[d] = base + pref[t];
      la[d] = hist[t] ? wsum[t] / (float)hist[t] : 0.f;
    }
  }
  for (int i = t; i < n; i += 256) {
    int2 it = stage[base + i];
    int bin = (it.y >> 16) & 127;
    int r = atomicAdd(&cur[bin], 1);
    edges[base + pref[bin] + r] = it;
  }
}

// ---------- standalone GEMM (bf16 A) ----------
template<bool DUAL>
__global__ __launch_bounds__(256) void k_gemm(
    const u16* __restrict__ A, const u16* __restrict__ WT,
    const u16* __restrict__ avs, const u16* __restrict__ avd,
    u16* __restrict__ xl, float* __restrict__ asrc, float* __restrict__ adst,
    float2* __restrict__ asAB, float* __restrict__ adstB, int n) {
  gemm_body<DUAL>(blockIdx.x, 0, A, WT, avs, avd, xl, asrc, adst, asAB, adstB, n);
}

// ---------- FUSED softmax+aggregation, 16 lanes/node, unroll-4 int4 gathers ----------
__global__ __launch_bounds__(256) void k_agg(
    const int* __restrict__ row_off, const int2* __restrict__ edges,
    const float* __restrict__ asrc, const float* __restrict__ adst,
    const float* __restrict__ la, const float* __restrict__ cptr,
    const u16* __restrict__ xl, const u16* __restrict__ bias,
    u16* __restrict__ out, int n) {
  __shared__ float lp[16][16];
  __shared__ int lsv[16][16];
  int tid = blockIdx.x * 256 + threadIdx.x;
  int d = tid >> 4;
  if (d >= n) return;
  int l = threadIdx.x & 15;
  int grp = threadIdx.x >> 4;
  float c = cptr[0];
  float ad = adst[d];
  float aL = lrelu(asrc[d] + ad + c * la[d]);
  float lsum = 0.f;
  int4 su = *(const int4*)(xl + (size_t)d * 128 + l * 8);
  float A0 = lo_f(su.x), A1 = hi_f(su.x), A2 = lo_f(su.y), A3 = hi_f(su.y);
  float A4 = lo_f(su.z), A5 = hi_f(su.z), A6 = lo_f(su.w), A7 = hi_f(su.w);
  float B0 = 0.f, B1 = 0.f, B2 = 0.f, B3 = 0.f, B4 = 0.f, B5 = 0.f, B6 = 0.f, B7 = 0.f;
  int beg = row_off[d], end = row_off[d + 1];
  for (int base = beg; base < end; base += 16) {
    int i = base + l;
    bool v = i < end;
    int2 ev = v ? edges[i] : make_int2(0, 0);
    float e = 0.f;
    if (v) e = __expf(lrelu(asrc[ev.x] + ad + c * bf2f((u16)(ev.y & 0xffff))) - aL);
    lsum += e;
    lp[grp][l] = e; lsv[grp][l] = ev.x;
    int cnt = end - base; if (cnt > 16) cnt = 16;
    int j = 0;
    for (; j + 4 <= cnt; j += 4) {   // 4 loads in flight per thread
      float p0 = lp[grp][j + 0]; int s0 = lsv[grp][j + 0];
      float p1 = lp[grp][j + 1]; int s1 = lsv[grp][j + 1];
      float p2 = lp[grp][j + 2]; int s2 = lsv[grp][j + 2];
      float p3 = lp[grp][j + 3]; int s3 = lsv[grp][j + 3];
      int4 u0 = *(const int4*)(xl + (size_t)s0 * 128 + l * 8);
      int4 u1 = *(const int4*)(xl + (size_t)s1 * 128 + l * 8);
      int4 u2 = *(const int4*)(xl + (size_t)s2 * 128 + l * 8);
      int4 u3 = *(const int4*)(xl + (size_t)s3 * 128 + l * 8);
      A0 = fmaf(p0, lo_f(u0.x), A0); A1 = fmaf(p0, hi_f(u0.x), A1);
      A2 = fmaf(p0, lo_f(u0.y), A2); A3 = fmaf(p0, hi_f(u0.y), A3);
      A4 = fmaf(p0, lo_f(u0.z), A4); A5 = fmaf(p0, hi_f(u0.z), A5);
      A6 = fmaf(p0, lo_f(u0.w), A6); A7 = fmaf(p0, hi_f(u0.w), A7);
      B0 = fmaf(p1, lo_f(u1.x), B0); B1 = fmaf(p1, hi_f(u1.x), B1);
      B2 = fmaf(p1, lo_f(u1.y), B2); B3 = fmaf(p1, hi_f(u1.y), B3);
      B4 = fmaf(p1, lo_f(u1.z), B4); B5 = fmaf(p1, hi_f(u1.z), B5);
      B6 = fmaf(p1, lo_f(u1.w), B6); B7 = fmaf(p1, hi_f(u1.w), B7);
      A0 = fmaf(p2, lo_f(u2.x), A0); A1 = fmaf(p2, hi_f(u2.x), A1);
      A2 = fmaf(p2, lo_f(u2.y), A2); A3 = fmaf(p2, hi_f(u2.y), A3);
      A4 = fmaf(p2, lo_f(u2.z), A4); A5 = fmaf(p2, hi_f(u2.z), A5);
      A6 = fmaf(p2, lo_f(u2.w), A6); A7 = fmaf(p2, hi_f(u2.w), A7);
      B0 = fmaf(p3, lo_f(u3.x), B0); B1 = fmaf(p3, hi_f(u3.x), B1);
      B2 = fmaf(p3, lo_f(u3.y), B2); B3 = fmaf(p3, hi_f(u3.y), B3);
      B4 = fmaf(p3, lo_f(u3.z), B4); B5 = fmaf(p3, hi_f(u3.z), B5);
      B6 = fmaf(p3, lo_f(u3.w), B6); B7 = fmaf(p3, hi_f(u3.w), B7);
    }
    for (; j + 2 <= cnt; j += 2) {
      float p0 = lp[grp][j];     int s0 = lsv[grp][j];
      float p1 = lp[grp][j + 1]; int s1 = lsv[grp][j + 1];
      int4 u0 = *(const int4*)(xl + (size_t)s0 * 128 + l * 8);
      int4 u1 = *(const int4*)(xl + (size_t)s1 * 128 + l * 8);
      A0 = fmaf(p0, lo_f(u0.x), A0); A1 = fmaf(p0, hi_f(u0.x), A1);
      A2 = fmaf(p0, lo_f(u0.y), A2); A3 = fmaf(p0, hi_f(u0.y), A3);
      A4 = fmaf(p0, lo_f(u0.z), A4); A5 = fmaf(p0, hi_f(u0.z), A5);
      A6 = fmaf(p0, lo_f(u0.w), A6); A7 = fmaf(p0, hi_f(u0.w), A7);
      B0 = fmaf(p1, lo_f(u1.x), B0); B1 = fmaf(p1, hi_f(u1.x), B1);
      B2 = fmaf(p1, lo_f(u1.y), B2); B3 = fmaf(p1, hi_f(u1.y), B3);
      B4 = fmaf(p1, lo_f(u1.z), B4); B5 = fmaf(p1, hi_f(u1.z), B5);
      B6 = fmaf(p1, lo_f(u1.w), B6); B7 = fmaf(p1, hi_f(u1.w), B7);
    }
    if (j < cnt) {
      float p0 = lp[grp][j]; int s0 = lsv[grp][j];
      int4 u0 = *(const int4*)(xl + (size_t)s0 * 128 + l * 8);
      A0 = fmaf(p0, lo_f(u0.x), A0); A1 = fmaf(p0, hi_f(u0.x), A1);
      A2 = fmaf(p0, lo_f(u0.y), A2); A3 = fmaf(p0, hi_f(u0.y), A3);
      A4 = fmaf(p0, lo_f(u0.z), A4); A5 = fmaf(p0, hi_f(u0.z), A5);
      A6 = fmaf(p0, lo_f(u0.w), A6); A7 = fmaf(p0, hi_f(u0.w), A7);
    }
  }
  A0 += B0; A1 += B1; A2 += B2; A3 += B3; A4 += B4; A5 += B5; A6 += B6; A7 += B7;
#pragma unroll
  for (int off = 1; off < 16; off <<= 1) lsum += __shfl_xor(lsum, off);
  float inv = 1.f / (lsum + 1.f);
  int4 bv = *(const int4*)(bias + l * 8);
  float o0 = fmaxf(fmaf(A0, inv, lo_f((unsigned)bv.x)), 0.f);
  float o1 = fmaxf(fmaf(A1, inv, hi_f((unsigned)bv.x)), 0.f);
  float o2 = fmaxf(fmaf(A2, inv, lo_f((unsigned)bv.y)), 0.f);
  float o3 = fmaxf(fmaf(A3, inv, hi_f((unsigned)bv.y)), 0.f);
  float o4 = fmaxf(fmaf(A4, inv, lo_f((unsigned)bv.z)), 0.f);
  float o5 = fmaxf(fmaf(A5, inv, hi_f((unsigned)bv.z)), 0.f);
  float o6 = fmaxf(fmaf(A6, inv, lo_f((unsigned)bv.w)), 0.f);
  float o7 = fmaxf(fmaf(A7, inv, hi_f((unsigned)bv.w)), 0.f);
  int4 ov;
  ov.x = (int)pack2(o0, o1); ov.y = (int)pack2(o2, o3);
  ov.z = (int)pack2(o4, o5); ov.w = (int)pack2(o6, o7);
  *(int4*)(out + (size_t)d * 128 + l * 8) = ov;
}

// ---------- FUSED dual-head, 16 lanes/node, unroll-4: lanes 0-7 mu, 8-15 logstd ----------
__global__ __launch_bounds__(256) void k_aggh(
    const int* __restrict__ row_off, const int2* __restrict__ edges,
    const float2* __restrict__ asAB, const float* __restrict__ adA,
    const float* __restrict__ adB,
    const float* __restrict__ la, const float* __restrict__ cptr,
    const u16* __restrict__ xl, const u16* __restrict__ bias,
    float* __restrict__ outf, int n) {
  __shared__ float lpA[16][16];
  __shared__ float lpB[16][16];
  __shared__ int lsv[16][16];
  int tid = blockIdx.x * 256 + threadIdx.x;
  int d = tid >> 4;
  if (d >= n) return;
  int l = threadIdx.x & 15;
  int grp = threadIdx.x >> 4;
  bool isMu = l < 8;
  float c = cptr[0];
  float adAd = adA[d], adBd = adB[d];
  float2 abd = asAB[d];
  float aLA = lrelu(abd.x + adAd + c * la[d]);
  float aLB = lrelu(abd.y + adBd);
  float lsA = 0.f, lsB = 0.f;
  int4 su = *(const int4*)(xl + (size_t)d * 128 + l * 8);
  float A0 = lo_f(su.x), A1 = hi_f(su.x), A2 = lo_f(su.y), A3 = hi_f(su.y);
  float A4 = lo_f(su.z), A5 = hi_f(su.z), A6 = lo_f(su.w), A7 = hi_f(su.w);
  float B0 = 0.f, B1 = 0.f, B2 = 0.f, B3 = 0.f, B4 = 0.f, B5 = 0.f, B6 = 0.f, B7 = 0.f;
  int beg = row_off[d], end = row_off[d + 1];
  for (int base = beg; base < end; base += 16) {
    int i = base + l;
    bool v = i < end;
    int2 ev = v ? edges[i] : make_int2(0, 0);
    float eA = 0.f, eB = 0.f;
    if (v) {
      float2 ab = asAB[ev.x];
      eA = __expf(lrelu(ab.x + adAd + c * bf2f((u16)(ev.y & 0xffff))) - aLA);
      eB = __expf(lrelu(ab.y + adBd) - aLB);
    }
    lsA += eA; lsB += eB;
    lpA[grp][l] = eA; lpB[grp][l] = eB; lsv[grp][l] = ev.x;
    const float* lpp = isMu ? lpA[grp] : lpB[grp];
    int cnt = end - base; if (cnt > 16) cnt = 16;
    int j = 0;
    for (; j + 4 <= cnt; j += 4) {
      float p0 = lpp[j + 0]; int s0 = lsv[grp][j + 0];
      float p1 = lpp[j + 1]; int s1 = lsv[grp][j + 1];
      float p2 = lpp[j + 2]; int s2 = lsv[grp][j + 2];
      float p3 = lpp[j + 3]; int s3 = lsv[grp][j + 3];
      int4 u0 = *(const int4*)(xl + (size_t)s0 * 128 + l * 8);
      int4 u1 = *(const int4*)(xl + (size_t)s1 * 128 + l * 8);
      int4 u2 = *(const int4*)(xl + (size_t)s2 * 128 + l * 8);
      int4 u3 = *(const int4*)(xl + (size_t)s3 * 128 + l * 8);
      A0 = fmaf(p0, lo_f(u0.x), A0); A1 = fmaf(p0, hi_f(u0.x), A1);
      A2 = fmaf(p0, lo_f(u0.y), A2); A3 = fmaf(p0, hi_f(u0.y), A3);
      A4 = fmaf(p0, lo_f(u0.z), A4); A5 = fmaf(p0, hi_f(u0.z), A5);
      A6 = fmaf(p0, lo_f(u0.w), A6); A7 = fmaf(p0, hi_f(u0.w), A7);
      B0 = fmaf(p1, lo_f(u1.x), B0); B1 = fmaf(p1, hi_f(u1.x), B1);
      B2 = fmaf(p1, lo_f(u1.y), B2); B3 = fmaf(p1, hi_f(u1.y), B3);
      B4 = fmaf(p1, lo_f(u1.z), B4); B5 = fmaf(p1, hi_f(u1.z), B5);
      B6 = fmaf(p1, lo_f(u1.w), B6); B7 = fmaf(p1, hi_f(u1.w), B7);
      A0 = fmaf(p2, lo_f(u2.x), A0); A1 = fmaf(p2, hi_f(u2.x), A1);
      A2 = fmaf(p2, lo_f(u2.y), A2); A3 = fmaf(p2, hi_f(u2.y), A3);
      A4 = fmaf(p2, lo_f(u2.z), A4); A5 = fmaf(p2, hi_f(u2.z), A5);
      A6 = fmaf(p2, lo_f(u2.w), A6); A7 = fmaf(p2, hi_f(u2.w), A7);
      B0 = fmaf(p3, lo_f(u3.x), B0); B1 = fmaf(p3, hi_f(u3.x), B1);
      B2 = fmaf(p3, lo_f(u3.y), B2); B3 = fmaf(p3, hi_f(u3.y), B3);
      B4 = fmaf(p3, lo_f(u3.z), B4); B5 = fmaf(p3, hi_f(u3.z), B5);
      B6 = fmaf(p3, lo_f(u3.w), B6); B7 = fmaf(p3, hi_f(u3.w), B7);
    }
    for (; j + 2 <= cnt; j += 2) {
      float p0 = lpp[j];     int s0 = lsv[grp][j];
      float p1 = lpp[j + 1]; int s1 = lsv[grp][j + 1];
      int4 u0 = *(const int4*)(xl + (size_t)s0 * 128 + l * 8);
      int4 u1 = *(const int4*)(xl + (size_t)s1 * 128 + l * 8);
      A0 = fmaf(p0, lo_f(u0.x), A0); A1 = fmaf(p0, hi_f(u0.x), A1);
      A2 = fmaf(p0, lo_f(u0.y), A2); A3 = fmaf(p0, hi_f(u0.y), A3);
      A4 = fmaf(p0, lo_f(u0.z), A4); A5 = fmaf(p0, hi_f(u0.z), A5);
      A6 = fmaf(p0, lo_f(u0.w), A6); A7 = fmaf(p0, hi_f(u0.w), A7);
      B0 = fmaf(p1, lo_f(u1.x), B0); B1 = fmaf(p1, hi_f(u1.x), B1);
      B2 = fmaf(p1, lo_f(u1.y), B2); B3 = fmaf(p1, hi_f(u1.y), B3);
      B4 = fmaf(p1, lo_f(u1.z), B4); B5 = fmaf(p1, hi_f(u1.z), B5);
      B6 = fmaf(p1, lo_f(u1.w), B6); B7 = fmaf(p1, hi_f(u1.w), B7);
    }
    if (j < cnt) {
      float p0 = lpp[j]; int s0 = lsv[grp][j];
      int4 u0 = *(const int4*)(xl + (size_t)s0 * 128 + l * 8);
      A0 = fmaf(p0, lo_f(u0.x), A0); A1 = fmaf(p0, hi_f(u0.x), A1);
      A2 = fmaf(p0, lo_f(u0.y), A2); A3 = fmaf(p0, hi_f(u0.y), A3);
      A4 = fmaf(p0, lo_f(u0.z), A4); A5 = fmaf(p0, hi_f(u0.z), A5);
      A6 = fmaf(p0, lo_f(u0.w), A6); A7 = fmaf(p0, hi_f(u0.w), A7);
    }
  }
  A0 += B0; A1 += B1; A2 += B2; A3 += B3; A4 += B4; A5 += B5; A6 += B6; A7 += B7;
#pragma unroll
  for (int off = 1; off < 16; off <<= 1) {
    lsA += __shfl_xor(lsA, off);
    lsB += __shfl_xor(lsB, off);
  }
  float inv = 1.f / ((isMu ? lsA : lsB) + 1.f);
  int4 bv = *(const int4*)(bias + l * 8);
  float4 oa, ob;
  oa.x = fmaf(A0, inv, lo_f((unsigned)bv.x));
  oa.y = fmaf(A1, inv, hi_f((unsigned)bv.x));
  oa.z = fmaf(A2, inv, lo_f((unsigned)bv.y));
  oa.w = fmaf(A3, inv, hi_f((unsigned)bv.y));
  ob.x = fmaf(A4, inv, lo_f((unsigned)bv.z));
  ob.y = fmaf(A5, inv, hi_f((unsigned)bv.z));
  ob.z = fmaf(A6, inv, lo_f((unsigned)bv.w));
  ob.w = fmaf(A7, inv, hi_f((unsigned)bv.w));
  float* obase = isMu ? (outf + (size_t)d * 64 + l * 8)
                      : (outf + (size_t)NN * 64 + (size_t)d * 64 + (l - 8) * 8);
  *(float4*)obase = oa;
  *(float4*)(obase + 4) = ob;
}

extern "C" void kernel_launch(void* const* d_in, const int* in_sizes, int n_in,
                              void* d_out, int out_size, void* d_ws, size_t ws_size,
                              hipStream_t stream) {
  (void)in_sizes; (void)n_in;
  const int* ei = (const int*)d_in[1];
  const u16* xb = (const u16*)d_in[0];
  float* outf = (float*)d_out;  // fp32 output

  // d_out scratch (dead before its region is written as output):
  //   histM: [0 .. 1.23MB)            consumed by k_esgemm/scanA
  //   stage: [2MB .. 14.8MB)          consumed by k_bucket (before agg L1 -> h1)
  u16* regionA = (u16*)d_out;                     // h1 (agg L1 output)
  u16* regionB = (u16*)d_out + (size_t)NN * 128;  // h0 (agg L0 output)
  int* histM = (int*)d_out;
  int2* stage = (int2*)((char*)d_out + (size_t)2 * 1024 * 1024);

  char* p = (char*)d_ws;
  auto alloc = [&](size_t bytes) -> char* {
    char* r = p; p += (bytes + 255) & ~(size_t)255; return r;
  };
  int*   row_off   = (int*)alloc((NN + 1) * 4);
  int*   binTot    = (int*)alloc(NBKP * 4);
  int*   bucketBase= (int*)alloc((NBKP + 2) * 4);
  float* la        = (float*)alloc(NN * 4);
  float* asrcA     = (float*)alloc(NN * 4);
  float* adstA     = (float*)alloc(NN * 4);
  float* adstB     = (float*)alloc(NN * 4);
  float2* asAB     = (float2*)alloc((size_t)NN * 8);
  int2*  edges     = (int2*)alloc((size_t)EE * 8);   // final CSR {src, low7|w}
  u16*   WT0       = (u16*)alloc(128 * 128 * 2);
  u16*   WT1       = (u16*)alloc(128 * 128 * 2);
  u16*   WTh       = (u16*)alloc(128 * 128 * 2);
  float* cvals     = (float*)alloc(16);
  u16*   vecc      = (u16*)alloc(9 * 256);
  u16*   xl        = (u16*)alloc((size_t)NN * 128 * 2);  // 25.6 MB

  size_t NEED = (size_t)(p - (char*)d_ws);  // ~41.3 MB
  if (ws_size < NEED) {
    k_fillf<<<(out_size + 255) / 256, 256, 0, stream>>>(outf, out_size, 0.125f);
    return;
  }

  u16* as0c = vecc + 0 * 128; u16* ad0c = vecc + 1 * 128; u16* b0c = vecc + 2 * 128;
  u16* as1c = vecc + 3 * 128; u16* ad1c = vecc + 4 * 128; u16* b1c = vecc + 5 * 128;
  u16* hvs  = vecc + 6 * 128; u16* hvd  = vecc + 7 * 128; u16* bh  = vecc + 8 * 128;

  // ---- fused setup + ehist ----
  SetupArgs sa;
  sa.cvt[0]  = {d_in[4],  as0c, 128};
  sa.cvt[1]  = {d_in[5],  ad0c, 128};
  sa.cvt[2]  = {d_in[8],  b0c,  128};
  sa.cvt[3]  = {d_in[10], as1c, 128};
  sa.cvt[4]  = {d_in[11], ad1c, 128};
  sa.cvt[5]  = {d_in[14], b1c,  128};
  sa.cvt[6]  = {d_in[16], hvs,      64};  // asm
  sa.cvt[7]  = {d_in[22], hvs + 64, 64};  // asl
  sa.cvt[8]  = {d_in[17], hvd,      64};  // adm
  sa.cvt[9]  = {d_in[23], hvd + 64, 64};  // adl
  sa.cvt[10] = {d_in[20], bh,       64};  // bm
  sa.cvt[11] = {d_in[24], bh + 64,  64};  // bl
  sa.W[0] = d_in[3];  sa.WT[0] = WT0;            sa.WM[0] = 128;
  sa.W[1] = d_in[9];  sa.WT[1] = WT1;            sa.WM[1] = 128;
  sa.W[2] = d_in[15]; sa.WT[2] = WTh;            sa.WM[2] = 64;  // Wm -> rows 0-63
  sa.W[3] = d_in[21]; sa.WT[3] = WTh + 64 * 128; sa.WM[3] = 64;  // Wl -> rows 64-127
  sa.dw[0] = d_in[7];  sa.da[0] = d_in[6];  sa.dm[0] = 128;
  sa.dw[1] = d_in[13]; sa.da[1] = d_in[12]; sa.dm[1] = 128;
  sa.dw[2] = d_in[19]; sa.da[2] = d_in[18]; sa.dm[2] = 64;
  sa.cvals = cvals; sa.xb = xb; sa.ei = ei; sa.histM = histM;
  k_setup<<<SETB + NBLK, 256, 0, stream>>>(sa);

  const int gblocks = (((NN + 15) / 16) + 3) / 4;
  const int eblocks16 = (int)(((size_t)NN * 16 + 255) / 256);

  // ---- CSR offsets ----
  k_scanA<<<NBK, 512, 0, stream>>>(histM, binTot);
  k_scanB<<<1, 256, 0, stream>>>(binTot, bucketBase, row_off);
  // ---- bucket scatter co-resident with layer-0 GEMM (independent) ----
  k_esgemm<<<NBLK + gblocks, 256, 0, stream>>>(ei, d_in[2], xb, histM, bucketBase,
                                               stage, d_in[0], WT0, as0c, ad0c,
                                               xl, asrcA, adstA, NN);
  k_bucket<<<NBK, 256, 0, stream>>>(stage, bucketBase, edges, row_off, la);

  // ---- layer 0 aggregation: xl -> h0(regionB) ----
  k_agg<<<eblocks16, 256, 0, stream>>>(row_off, edges, asrcA, adstA, la,
                                       cvals + 0, xl, b0c, regionB, NN);
  // ---- layer 1 ----
  k_gemm<false><<<gblocks, 256, 0, stream>>>(regionB, WT1, as1c, ad1c,
                                             xl, asrcA, adstA, nullptr, nullptr, NN);
  k_agg<<<eblocks16, 256, 0, stream>>>(row_off, edges, asrcA, adstA, la,
                                       cvals + 1, xl, b1c, regionA, NN);
  // ---- heads ----
  k_gemm<true><<<gblocks, 256, 0, stream>>>(regionA, WTh, hvs, hvd,
                                            xl, nullptr, adstA, asAB, adstB, NN);
  k_aggh<<<eblocks16, 256, 0, stream>>>(row_off, edges, asAB, adstA, adstB,
                                        la, cvals + 2, xl, bh, outf, NN);
}